// Round 4
// baseline (1240.883 us; speedup 1.0000x reference)
//
#include <hip/hip_runtime.h>

typedef _Float16 f16;
typedef _Float16 f16x8 __attribute__((ext_vector_type(8)));
typedef float    f32x4 __attribute__((ext_vector_type(4)));
typedef unsigned int u32;
typedef u32 u32x4 __attribute__((ext_vector_type(4)));

#define CCH 66
#define LLEN 100
#define BSZ 4096
#define NPAD 2048
#define NOUT 1936
#define KFEAT 7128
#define FPC 112                 // padded features per channel (108 real + 4 zero)
#define KF2 (CCH * FPC)         // 7392
#define KP2 7424                // KF2 padded to x32
#define NCH2 (KP2 / 8)          // 928 chunk-rows in feats2
#define ROWE (BSZ * 8)          // f16 elements per chunk-row (32768)
#define LC (LLEN * CCH)
#define XROWS 106               // 100 real l-rows + 6 zero halo

// ---------------------------------------------------------------- async G->LDS
typedef __attribute__((address_space(1))) const u32 gu32;
typedef __attribute__((address_space(3))) u32 lu32;

__device__ __forceinline__ void gload_lds16(const void* g, void* l) {
    __builtin_amdgcn_global_load_lds((gu32*)g, (lu32*)l, 16, 0, 0);
}

__device__ __forceinline__ u32 pk(f16 lo, f16 hi) {
    unsigned short a = __builtin_bit_cast(unsigned short, lo);
    unsigned short b = __builtin_bit_cast(unsigned short, hi);
    return (u32)a | ((u32)b << 16);
}

// ---------------------------------------------------------------- x transpose
// x [B][L*C] f32  ->  xT [L*C][B] f16   (element (l,c) row index = l*66+c)
__global__ __launch_bounds__(256) void transpose_x(const float* __restrict__ x,
                                                   f16* __restrict__ xT) {
    __shared__ float tile[32][33];
    const int m0 = blockIdx.x * 32;           // lc index
    const int b0 = blockIdx.y * 32;           // batch index
    const int tx = threadIdx.x & 31, ty = threadIdx.x >> 5;  // 32 x 8
#pragma unroll
    for (int i = 0; i < 32; i += 8) {
        int m = m0 + tx, b = b0 + ty + i;
        tile[ty + i][tx] = (m < LC) ? x[(size_t)b * LC + m] : 0.f;
    }
    __syncthreads();
#pragma unroll
    for (int i = 0; i < 32; i += 8) {
        int m = m0 + ty + i, b = b0 + tx;
        if (m < LC) xT[(size_t)m * BSZ + b] = (f16)tile[tx][ty + i];
    }
}

// ---------------------------------------------------------------- feature pipeline
// x for this (c, b-block) lives in LDS: xl[l*256 + tid], l in [0,106), rows
// 100..105 are zeros.  All indices below are compile-time after full unroll.
__device__ __forceinline__ float ldx(const f16* __restrict__ xl, int tid, int u) {
    return (u >= 0) ? (float)xl[u * 256 + tid] : 0.f;
}

// paired hp1 columns idx, idx+1 (idx compile-time)
template<int K>
__device__ __forceinline__ void hp1_pair(const f16* __restrict__ xl, int tid, int idx,
                                         const float* __restrict__ w1,
                                         const float* __restrict__ b1,
                                         float colA[8], float colB[8]) {
    constexpr int P = K / 2;
    constexpr int W = K + 3;
    if (idx >= 50) {  // folds at compile time
#pragma unroll
        for (int ic = 0; ic < 8; ++ic) { colA[ic] = 0.f; colB[ic] = 0.f; }
        return;
    }
    float xv[W];
#pragma unroll
    for (int j = 0; j < W; ++j) xv[j] = ldx(xl, tid, 2 * idx - P + j);
    const bool vB = (idx + 1 < 50);
#pragma unroll
    for (int ic = 0; ic < 8; ++ic) {
        float a0 = b1[ic], a1 = b1[ic], a2 = b1[ic], a3 = b1[ic];
#pragma unroll
        for (int k = 0; k < K; ++k) {
            float w = w1[ic * K + k];
            a0 += w * xv[k];
            a1 += w * xv[k + 1];
            a2 += w * xv[k + 2];
            a3 += w * xv[k + 3];
        }
        colA[ic] = 0.5f * (fmaxf(a0, 0.f) + fmaxf(a1, 0.f));
        colB[ic] = vB ? 0.5f * (fmaxf(a2, 0.f) + fmaxf(a3, 0.f)) : 0.f;
    }
}

// Fully-unrolled branch; outputs packed into outw[24] u32 (= out[oc][t] f16,
// outw[oc*6 + t/2], t low half first).
template<int K>
__device__ __forceinline__ void run_branch_u(const f16* __restrict__ xl, int tid,
                                             const float* __restrict__ w1, const float* __restrict__ b1,
                                             const float* __restrict__ w2, const float* __restrict__ b2,
                                             const float* __restrict__ w3, const float* __restrict__ b3,
                                             u32 outw[24]) {
    constexpr int P = K / 2;
    float W1[8][K + 1];
    float W2[4][K];
#pragma unroll
    for (int ic = 0; ic < 8; ++ic)
#pragma unroll
        for (int j = 0; j <= K; ++j) W1[ic][j] = 0.f;
#pragma unroll
    for (int oc = 0; oc < 4; ++oc)
#pragma unroll
        for (int j = 0; j < K; ++j) W2[oc][j] = 0.f;

    // prologue: W1[.][P+idx] = hp1[idx] for idx = 0..P+1
#pragma unroll
    for (int idx = 0; idx <= P + 1; idx += 2) {
        float cA[8], cB[8];
        hp1_pair<K>(xl, tid, idx, w1, b1, cA, cB);
#pragma unroll
        for (int ic = 0; ic < 8; ++ic) {
            W1[ic][P + idx] = cA[ic];
            if (idx + 1 <= P + 1) W1[ic][P + idx + 1] = cB[ic];
        }
    }

    float pacc[4] = {0.f, 0.f, 0.f, 0.f};
    f16 pend[4];
    constexpr int SMAX = 23 + P;  // last y3 position p = 23
#pragma unroll
    for (int s = 0; s <= SMAX; ++s) {
        // hp2[s] from y2 at 2s, 2s+1
        float h2col[4];
        if (s <= 24) {
#pragma unroll
            for (int oc = 0; oc < 4; ++oc) {
                float ya = b2[oc], yb = b2[oc];
#pragma unroll
                for (int ic = 0; ic < 8; ++ic)
#pragma unroll
                    for (int k = 0; k < K; ++k) {
                        float w = w2[(oc * 8 + ic) * K + k];
                        ya += w * W1[ic][k];
                        yb += w * W1[ic][k + 1];
                    }
                h2col[oc] = 0.5f * (fmaxf(ya, 0.f) + fmaxf(yb, 0.f));
            }
        } else {
#pragma unroll
            for (int oc = 0; oc < 4; ++oc) h2col[oc] = 0.f;
        }
        // shift W2, append hp2[s]
#pragma unroll
        for (int oc = 0; oc < 4; ++oc) {
#pragma unroll
            for (int j = 0; j < K - 1; ++j) W2[oc][j] = W2[oc][j + 1];
            W2[oc][K - 1] = h2col[oc];
        }
        // y3 at p = s - P; pool pairs -> output t = p>>1
        constexpr int PP = P;
        int p = s - PP;
        if (p >= 0) {
            float y3[4];
#pragma unroll
            for (int oc = 0; oc < 4; ++oc) {
                float y = b3[oc];
#pragma unroll
                for (int ic = 0; ic < 4; ++ic)
#pragma unroll
                    for (int k = 0; k < K; ++k)
                        y += w3[(oc * 4 + ic) * K + k] * W2[ic][k];
                y3[oc] = fmaxf(y, 0.f);
            }
            if ((p & 1) == 0) {
#pragma unroll
                for (int oc = 0; oc < 4; ++oc) pacc[oc] = y3[oc];
            } else {
                int t = p >> 1;
                if ((t & 1) == 0) {
#pragma unroll
                    for (int oc = 0; oc < 4; ++oc)
                        pend[oc] = (f16)(0.5f * (pacc[oc] + y3[oc]));
                } else {
#pragma unroll
                    for (int oc = 0; oc < 4; ++oc)
                        outw[oc * 6 + (t >> 1)] = pk(pend[oc], (f16)(0.5f * (pacc[oc] + y3[oc])));
                }
            }
        }
        // advance W1 by 2 columns
        if (s < SMAX) {
#pragma unroll
            for (int ic = 0; ic < 8; ++ic)
#pragma unroll
                for (int j = 0; j < K - 1; ++j) W1[ic][j] = W1[ic][j + 2];
            float colA[8], colB[8];
            hp1_pair<K>(xl, tid, 2 * s + P + 2, w1, b1, colA, colB);
#pragma unroll
            for (int ic = 0; ic < 8; ++ic) {
                W1[ic][K - 1] = colA[ic];
                W1[ic][K]     = colB[ic];
            }
        }
    }
}

// feats2 blocked layout: element (b, k = c*112 + f) lives at
//   feats2[(c*14 + (f>>3)) * ROWE + b*8 + (f&7)]
__global__ __launch_bounds__(256, 3) void feats_kernel(
    const f16* __restrict__ xT,
    const float* __restrict__ hw1, const float* __restrict__ hb1,
    const float* __restrict__ hw2, const float* __restrict__ hb2,
    const float* __restrict__ hw3, const float* __restrict__ hb3,
    const float* __restrict__ lw1, const float* __restrict__ lb1,
    const float* __restrict__ lw2, const float* __restrict__ lb2,
    const float* __restrict__ lw3, const float* __restrict__ lb3,
    f16* __restrict__ feats2) {
    __shared__ f16 xlds[XROWS * 256];   // 54272 B -> 3 blocks/CU
    const int c = blockIdx.x;
    const int tid = threadIdx.x;
    const int bb0 = blockIdx.y * 256;
    const int b = bb0 + tid;

    // ---- stage x rows 0..99 into LDS (coalesced, async), halo rows 100..105 = 0
#pragma unroll
    for (int i = 0; i < 13; ++i) {
        int q = i * 256 + tid;               // 16B chunk id; 32 chunks per row
        if (q < 100 * 32) {
            int row = q >> 5, cl = q & 31;
            gload_lds16(xT + (size_t)(row * CCH + c) * BSZ + bb0 + cl * 8,
                        (char*)xlds + (size_t)q * 16);
        }
    }
    if (tid < 192) {                          // 6 halo rows x 512 B = 192 chunks
        *(u32x4*)((char*)xlds + (size_t)(3200 + tid) * 16) = (u32x4){0u, 0u, 0u, 0u};
    }
    __syncthreads();

    // ---- compute (all x reads from LDS, all output packing in registers)
    u32 oh[24], ol[24], orr[6];
    run_branch_u<7>(xlds, tid, hw1 + c * 56, hb1 + c * 8, hw2 + c * 224, hb2 + c * 4,
                    hw3 + c * 112, hb3 + c * 4, oh);
    run_branch_u<3>(xlds, tid, lw1 + c * 24, lb1 + c * 8, lw2 + c * 96, lb2 + c * 4,
                    lw3 + c * 48, lb3 + c * 4, ol);
    // residual pooling: features 96..107
#pragma unroll
    for (int t2 = 0; t2 < 6; ++t2) {
        float s0 = 0.f, s1 = 0.f;
#pragma unroll
        for (int j = 0; j < 8; ++j) {
            s0 += ldx(xlds, tid, 16 * t2 + j);
            s1 += ldx(xlds, tid, 16 * t2 + 8 + j);
        }
        orr[t2] = pk((f16)(s0 * 0.125f), (f16)(s1 * 0.125f));
    }

    // ---- coalesced stores: 14 x dwordx4 per thread
    u32* dst = (u32*)feats2 + (size_t)c * 14 * (ROWE / 2) + (size_t)b * 4;
#pragma unroll
    for (int ch = 0; ch < 6; ++ch)
        *(u32x4*)(dst + (size_t)ch * (ROWE / 2)) =
            (u32x4){oh[ch * 4], oh[ch * 4 + 1], oh[ch * 4 + 2], oh[ch * 4 + 3]};
#pragma unroll
    for (int ch = 0; ch < 6; ++ch)
        *(u32x4*)(dst + (size_t)(6 + ch) * (ROWE / 2)) =
            (u32x4){ol[ch * 4], ol[ch * 4 + 1], ol[ch * 4 + 2], ol[ch * 4 + 3]};
    *(u32x4*)(dst + (size_t)12 * (ROWE / 2)) = (u32x4){orr[0], orr[1], orr[2], orr[3]};
    *(u32x4*)(dst + (size_t)13 * (ROWE / 2)) = (u32x4){orr[4], orr[5], 0u, 0u};
}

// zero the pad chunk-rows (k = 7392..7423 -> rows 924..927)
__global__ void zero_pad2(f16* __restrict__ feats2) {
    int idx = blockIdx.x * 256 + threadIdx.x;
    u32* dst = (u32*)(feats2 + (size_t)(CCH * 14) * ROWE);
    if (idx < (4 * ROWE * 2) / 16)
        *(u32x4*)(dst + idx * 4) = (u32x4){0u, 0u, 0u, 0u};
}

// convert fw1 (1936 x 7128 f32) -> padded f16 (2048 x 7424) with per-c pad
__global__ void cvt_fw1(const float* __restrict__ fw1, f16* __restrict__ dst) {
    int n = blockIdx.y;
    int kp = blockIdx.x * 256 + threadIdx.x;
    if (kp >= KP2) return;
    int c2 = kp / FPC, f = kp - c2 * FPC;
    float v = 0.f;
    if (n < NOUT && kp < KF2 && f < 108)
        v = fw1[(size_t)n * KFEAT + c2 * 108 + f];
    dst[(size_t)n * KP2 + kp] = (f16)v;
}

// ---------------------------------------------------------------- FC1 GEMM
// A in feats2 blocked layout; Bw [n][KP2]; H = relu(A.Bw^T + fb1) f16 [m][NPAD]
__global__ __launch_bounds__(256) void fc1_gemm(
    const f16* __restrict__ A, const f16* __restrict__ Bw,
    const float* __restrict__ fb1, f16* __restrict__ H) {
    __shared__ f16 lds_a[128 * 32];
    __shared__ f16 lds_b[128 * 32];
    const int tid = threadIdx.x;
    const int bm = blockIdx.x;  // 32 tiles of M
    const int bn = blockIdx.y;  // 16 tiles of N
    const int wid = tid >> 6, lane = tid & 63;
    const int wm = wid >> 1, wn = wid & 1;

    f32x4 acc[4][4];
#pragma unroll
    for (int i = 0; i < 4; ++i)
#pragma unroll
        for (int j = 0; j < 4; ++j) acc[i][j] = (f32x4){0.f, 0.f, 0.f, 0.f};

    const f16* Bbase = Bw + (size_t)bn * 128 * KP2;
    const int l15 = lane & 15, lhi = lane >> 4;

    const int flat0 = tid, flat1 = 256 + tid;
    const int row0 = flat0 >> 2, kc0 = flat0 & 3;
    const int row1 = flat1 >> 2, kc1 = flat1 & 3;

    for (int k0 = 0; k0 < KP2; k0 += 32) {
        __syncthreads();
        gload_lds16(A + (size_t)((k0 >> 3) + kc0) * ROWE + (size_t)(bm * 128 + row0) * 8,
                    (char*)lds_a + flat0 * 16);
        gload_lds16(A + (size_t)((k0 >> 3) + kc1) * ROWE + (size_t)(bm * 128 + row1) * 8,
                    (char*)lds_a + flat1 * 16);
        gload_lds16(Bbase + (size_t)row0 * KP2 + k0 + kc0 * 8, (char*)lds_b + flat0 * 16);
        gload_lds16(Bbase + (size_t)row1 * KP2 + k0 + kc1 * 8, (char*)lds_b + flat1 * 16);
        __syncthreads();

        f16x8 af[4], bf[4];
#pragma unroll
        for (int i = 0; i < 4; ++i) {
            int m = wm * 64 + i * 16 + l15;
            af[i] = *(const f16x8*)(lds_a + m * 32 + lhi * 8);
            int n = wn * 64 + i * 16 + l15;
            bf[i] = *(const f16x8*)(lds_b + n * 32 + lhi * 8);
        }
#pragma unroll
        for (int i = 0; i < 4; ++i)
#pragma unroll
            for (int j = 0; j < 4; ++j)
                acc[i][j] = __builtin_amdgcn_mfma_f32_16x16x32_f16(af[i], bf[j], acc[i][j], 0, 0, 0);
    }

    // epilogue: C/D layout col = lane&15, row = (lane>>4)*4 + r
#pragma unroll
    for (int i = 0; i < 4; ++i) {
#pragma unroll
        for (int j = 0; j < 4; ++j) {
            int n = bn * 128 + wn * 64 + j * 16 + l15;
            float bias = (n < NOUT) ? fb1[n] : 0.f;
#pragma unroll
            for (int r = 0; r < 4; ++r) {
                int m = bm * 128 + wm * 64 + i * 16 + lhi * 4 + r;
                float v = acc[i][j][r] + bias;
                H[(size_t)m * NPAD + n] = (f16)fmaxf(v, 0.f);
            }
        }
    }
}

// ---------------------------------------------------------------- FC2
__global__ __launch_bounds__(64) void fc2_kernel(const f16* __restrict__ H,
                                                 const float* __restrict__ fw2,
                                                 const float* __restrict__ fb2,
                                                 float* __restrict__ out) {
    const int b = blockIdx.x;
    const int t = threadIdx.x;
    const f16* hb = H + (size_t)b * NPAD;
    float acc[14];
#pragma unroll
    for (int o = 0; o < 14; ++o) acc[o] = 0.f;
    for (int k = t; k < NOUT; k += 64) {
        float hv = (float)hb[k];
#pragma unroll
        for (int o = 0; o < 14; ++o) acc[o] += hv * fw2[o * NOUT + k];
    }
#pragma unroll
    for (int o = 0; o < 14; ++o) {
        float v = acc[o];
#pragma unroll
        for (int off = 32; off > 0; off >>= 1) v += __shfl_down(v, off, 64);
        if (t == 0) out[b * 14 + o] = v + fb2[o];
    }
}

// ---------------------------------------------------------------- launcher
extern "C" void kernel_launch(void* const* d_in, const int* in_sizes, int n_in,
                              void* d_out, int out_size, void* d_ws, size_t ws_size,
                              hipStream_t stream) {
    const float* x   = (const float*)d_in[0];
    const float* hw1 = (const float*)d_in[1];
    const float* hb1 = (const float*)d_in[2];
    const float* hw2 = (const float*)d_in[3];
    const float* hb2 = (const float*)d_in[4];
    const float* hw3 = (const float*)d_in[5];
    const float* hb3 = (const float*)d_in[6];
    const float* lw1 = (const float*)d_in[7];
    const float* lb1 = (const float*)d_in[8];
    const float* lw2 = (const float*)d_in[9];
    const float* lb2 = (const float*)d_in[10];
    const float* lw3 = (const float*)d_in[11];
    const float* lb3 = (const float*)d_in[12];
    const float* fw1 = (const float*)d_in[13];
    const float* fb1 = (const float*)d_in[14];
    const float* fw2 = (const float*)d_in[15];
    const float* fb2 = (const float*)d_in[16];

    // workspace layout (xT and h alias: disjoint lifetimes)
    f16* feats2 = (f16*)d_ws;                               // 928*32768 f16 = 60.8 MB
    f16* fw1H   = feats2 + (size_t)NCH2 * ROWE;             // 2048*7424 f16 = 30.4 MB
    f16* xT     = fw1H + (size_t)NPAD * KP2;                // 6600*4096 f16 = 54.1 MB
    f16* h      = xT;                                       // 4096*2048 f16 = 16.8 MB (aliases xT)

    transpose_x<<<dim3((LC + 31) / 32, BSZ / 32), 256, 0, stream>>>(x, xT);
    feats_kernel<<<dim3(CCH, BSZ / 256), 256, 0, stream>>>(
        xT, hw1, hb1, hw2, hb2, hw3, hb3, lw1, lb1, lw2, lb2, lw3, lb3, feats2);
    zero_pad2<<<dim3(64), 256, 0, stream>>>(feats2);
    cvt_fw1<<<dim3((KP2 + 255) / 256, NPAD), 256, 0, stream>>>(fw1, fw1H);
    fc1_gemm<<<dim3(BSZ / 128, NPAD / 128), 256, 0, stream>>>(feats2, fw1H, fb1, h);
    fc2_kernel<<<dim3(BSZ), 64, 0, stream>>>(h, fw2, fb2, (float*)d_out);
}

// Round 5
// 1025.182 us; speedup vs baseline: 1.2104x; 1.2104x over previous
//
#include <hip/hip_runtime.h>

typedef _Float16 f16;
typedef _Float16 f16x8 __attribute__((ext_vector_type(8)));
typedef float    f32x4 __attribute__((ext_vector_type(4)));
typedef unsigned int u32;
typedef u32 u32x4 __attribute__((ext_vector_type(4)));

#define CCH 66
#define LLEN 100
#define BSZ 4096
#define NPAD 2048
#define NOUT 1936
#define KFEAT 7128
#define FPC 112                 // padded features per channel (108 real + 4 zero)
#define KF2 (CCH * FPC)         // 7392
#define KP2 7424                // KF2 padded to x32
#define NCH2 (KP2 / 8)          // 928 chunk-rows in feats2
#define ROWE (BSZ * 8)          // f16 elements per chunk-row (32768)
#define XSTR (CCH * BSZ)        // element stride between successive l in xT
#define LC (LLEN * CCH)
#define OSTR 25                 // obuf row stride in u32 (odd -> conflict-free)

// ---------------------------------------------------------------- async G->LDS
typedef __attribute__((address_space(1))) const u32 gu32;
typedef __attribute__((address_space(3))) u32 lu32;

__device__ __forceinline__ void gload_lds16(const void* g, void* l) {
    __builtin_amdgcn_global_load_lds((gu32*)g, (lu32*)l, 16, 0, 0);
}

__device__ __forceinline__ u32 pk(f16 lo, f16 hi) {
    unsigned short a = __builtin_bit_cast(unsigned short, lo);
    unsigned short b = __builtin_bit_cast(unsigned short, hi);
    return (u32)a | ((u32)b << 16);
}

// ---------------------------------------------------------------- x transpose
// x [B][L*C] f32  ->  xT [L*C][B] f16   (element (l,c) row index = l*66+c)
__global__ __launch_bounds__(256) void transpose_x(const float* __restrict__ x,
                                                   f16* __restrict__ xT) {
    __shared__ float tile[32][33];
    const int m0 = blockIdx.x * 32;           // lc index
    const int b0 = blockIdx.y * 32;           // batch index
    const int tx = threadIdx.x & 31, ty = threadIdx.x >> 5;  // 32 x 8
#pragma unroll
    for (int i = 0; i < 32; i += 8) {
        int m = m0 + tx, b = b0 + ty + i;
        tile[ty + i][tx] = (m < LC) ? x[(size_t)b * LC + m] : 0.f;
    }
    __syncthreads();
#pragma unroll
    for (int i = 0; i < 32; i += 8) {
        int m = m0 + ty + i, b = b0 + tx;
        if (m < LC) xT[(size_t)m * BSZ + b] = (f16)tile[tx][ty + i];
    }
}

// ---------------------------------------------------------------- feature pipeline
__device__ __forceinline__ float ldx(const f16* __restrict__ xb, int u) {
    return (float)xb[(size_t)u * XSTR];
}

// paired hp1 columns idx, idx+1 from one shared window of K+3 x values
template<int K>
__device__ __forceinline__ void hp1_pair(const f16* __restrict__ xb, int idx,
                                         const float* __restrict__ w1,
                                         const float* __restrict__ b1,
                                         float colA[8], float colB[8]) {
    constexpr int P = K / 2;
    constexpr int W = K + 3;
    float xv[W];
#pragma unroll
    for (int j = 0; j < W; ++j) {
        int u = 2 * idx - P + j;
        xv[j] = (u >= 0 && u < LLEN) ? ldx(xb, u) : 0.f;
    }
    const bool vA = (idx < 50), vB = (idx + 1 < 50);
#pragma unroll
    for (int ic = 0; ic < 8; ++ic) {
        float a0 = b1[ic], a1 = b1[ic], a2 = b1[ic], a3 = b1[ic];
#pragma unroll
        for (int k = 0; k < K; ++k) {
            float w = w1[ic * K + k];
            a0 += w * xv[k];
            a1 += w * xv[k + 1];
            a2 += w * xv[k + 2];
            a3 += w * xv[k + 3];
        }
        colA[ic] = vA ? 0.5f * (fmaxf(a0, 0.f) + fmaxf(a1, 0.f)) : 0.f;
        colB[ic] = vB ? 0.5f * (fmaxf(a2, 0.f) + fmaxf(a3, 0.f)) : 0.f;
    }
}

// Rolled-loop branch; packed outputs out[oc][t] (f16) go to LDS row orow as
// u32 word oc*6 + t/2 (dynamic ds_write; same-thread readback later).
template<int K>
__device__ __forceinline__ void run_branch(const f16* __restrict__ xb,
                                           const float* __restrict__ w1, const float* __restrict__ b1,
                                           const float* __restrict__ w2, const float* __restrict__ b2,
                                           const float* __restrict__ w3, const float* __restrict__ b3,
                                           u32* __restrict__ orow) {
    constexpr int P = K / 2;
    float W1[8][K + 1];
    float W2[4][K];
#pragma unroll
    for (int ic = 0; ic < 8; ++ic)
#pragma unroll
        for (int j = 0; j <= K; ++j) W1[ic][j] = 0.f;
#pragma unroll
    for (int oc = 0; oc < 4; ++oc)
#pragma unroll
        for (int j = 0; j < K; ++j) W2[oc][j] = 0.f;

    // prologue: W1[.][P+idx] = hp1[idx] for idx = 0..P+1
#pragma unroll
    for (int idx = 0; idx <= P + 1; idx += 2) {
        float cA[8], cB[8];
        hp1_pair<K>(xb, idx, w1, b1, cA, cB);
#pragma unroll
        for (int ic = 0; ic < 8; ++ic) {
            W1[ic][P + idx] = cA[ic];
            if (idx + 1 <= P + 1) W1[ic][P + idx + 1] = cB[ic];
        }
    }

    float pacc[4] = {0.f, 0.f, 0.f, 0.f};
    f16 pend[4] = {(f16)0.f, (f16)0.f, (f16)0.f, (f16)0.f};
    const int SMAX = 23 + P;  // last y3 position p = 23
#pragma unroll 4
    for (int s = 0; s <= SMAX; ++s) {
        // hp2[s] from y2 at 2s, 2s+1
        float h2col[4];
        if (s <= 24) {
#pragma unroll
            for (int oc = 0; oc < 4; ++oc) {
                float ya = b2[oc], yb = b2[oc];
#pragma unroll
                for (int ic = 0; ic < 8; ++ic)
#pragma unroll
                    for (int k = 0; k < K; ++k) {
                        float w = w2[(oc * 8 + ic) * K + k];
                        ya += w * W1[ic][k];
                        yb += w * W1[ic][k + 1];
                    }
                h2col[oc] = 0.5f * (fmaxf(ya, 0.f) + fmaxf(yb, 0.f));
            }
        } else {
#pragma unroll
            for (int oc = 0; oc < 4; ++oc) h2col[oc] = 0.f;
        }
        // shift W2, append hp2[s]
#pragma unroll
        for (int oc = 0; oc < 4; ++oc) {
#pragma unroll
            for (int j = 0; j < K - 1; ++j) W2[oc][j] = W2[oc][j + 1];
            W2[oc][K - 1] = h2col[oc];
        }
        // y3 at p = s - P; pool pairs -> packed output word at t = p>>1 pairs
        int p = s - P;
        if (p >= 0) {
            float y3[4];
#pragma unroll
            for (int oc = 0; oc < 4; ++oc) {
                float y = b3[oc];
#pragma unroll
                for (int ic = 0; ic < 4; ++ic)
#pragma unroll
                    for (int k = 0; k < K; ++k)
                        y += w3[(oc * 4 + ic) * K + k] * W2[ic][k];
                y3[oc] = fmaxf(y, 0.f);
            }
            if ((p & 1) == 0) {
#pragma unroll
                for (int oc = 0; oc < 4; ++oc) pacc[oc] = y3[oc];
            } else {
                int t = p >> 1;
                if ((t & 1) == 0) {
#pragma unroll
                    for (int oc = 0; oc < 4; ++oc)
                        pend[oc] = (f16)(0.5f * (pacc[oc] + y3[oc]));
                } else {
#pragma unroll
                    for (int oc = 0; oc < 4; ++oc)
                        orow[oc * 6 + (t >> 1)] = pk(pend[oc], (f16)(0.5f * (pacc[oc] + y3[oc])));
                }
            }
        }
        // advance W1 by 2 columns
        if (s < SMAX) {
#pragma unroll
            for (int ic = 0; ic < 8; ++ic)
#pragma unroll
                for (int j = 0; j < K - 1; ++j) W1[ic][j] = W1[ic][j + 2];
            float colA[8], colB[8];
            hp1_pair<K>(xb, 2 * s + P + 2, w1, b1, colA, colB);
#pragma unroll
            for (int ic = 0; ic < 8; ++ic) {
                W1[ic][K - 1] = colA[ic];
                W1[ic][K]     = colB[ic];
            }
        }
    }
}

// feats2 blocked layout: element (b, k = c*112 + f) lives at
//   feats2[(c*14 + (f>>3)) * ROWE + b*8 + (f&7)]
__global__ __launch_bounds__(256, 4) void feats_kernel(
    const f16* __restrict__ xT,
    const float* __restrict__ hw1, const float* __restrict__ hb1,
    const float* __restrict__ hw2, const float* __restrict__ hb2,
    const float* __restrict__ hw3, const float* __restrict__ hb3,
    const float* __restrict__ lw1, const float* __restrict__ lb1,
    const float* __restrict__ lw2, const float* __restrict__ lb2,
    const float* __restrict__ lw3, const float* __restrict__ lb3,
    f16* __restrict__ feats2) {
    __shared__ u32 obufw[256 * OSTR];   // 25.6 KB -> 6 blocks/CU
    const int c = blockIdx.x;
    const int tid = threadIdx.x;
    const int b = blockIdx.y * 256 + tid;
    const f16* xb = xT + (size_t)c * BSZ + b;  // element l at xb[l*XSTR]
    u32* orow = obufw + tid * OSTR;
    u32* dst = (u32*)feats2 + (size_t)c * 14 * (ROWE / 2) + (size_t)b * 4;

    // ---- high branch (K=7) -> chunks 0..5
    run_branch<7>(xb, hw1 + c * 56, hb1 + c * 8, hw2 + c * 224, hb2 + c * 4,
                  hw3 + c * 112, hb3 + c * 4, orow);
    {
        u32 v[24];
#pragma unroll
        for (int j = 0; j < 24; ++j) v[j] = orow[j];   // same-thread RAW, no barrier
#pragma unroll
        for (int ch = 0; ch < 6; ++ch)
            *(u32x4*)(dst + (size_t)ch * (ROWE / 2)) =
                (u32x4){v[ch * 4], v[ch * 4 + 1], v[ch * 4 + 2], v[ch * 4 + 3]};
    }

    // ---- low branch (K=3) -> chunks 6..11 (reuses orow)
    run_branch<3>(xb, lw1 + c * 24, lb1 + c * 8, lw2 + c * 96, lb2 + c * 4,
                  lw3 + c * 48, lb3 + c * 4, orow);
    {
        u32 v[24];
#pragma unroll
        for (int j = 0; j < 24; ++j) v[j] = orow[j];
#pragma unroll
        for (int ch = 0; ch < 6; ++ch)
            *(u32x4*)(dst + (size_t)(6 + ch) * (ROWE / 2)) =
                (u32x4){v[ch * 4], v[ch * 4 + 1], v[ch * 4 + 2], v[ch * 4 + 3]};
    }

    // ---- residual pooling -> chunks 12..13 (registers only, static indices)
    u32 orr[6];
#pragma unroll
    for (int t2 = 0; t2 < 6; ++t2) {
        float s0 = 0.f, s1 = 0.f;
#pragma unroll
        for (int j = 0; j < 8; ++j) {
            s0 += ldx(xb, 16 * t2 + j);
            s1 += ldx(xb, 16 * t2 + 8 + j);
        }
        orr[t2] = pk((f16)(s0 * 0.125f), (f16)(s1 * 0.125f));
    }
    *(u32x4*)(dst + (size_t)12 * (ROWE / 2)) = (u32x4){orr[0], orr[1], orr[2], orr[3]};
    *(u32x4*)(dst + (size_t)13 * (ROWE / 2)) = (u32x4){orr[4], orr[5], 0u, 0u};
}

// zero the pad chunk-rows (k = 7392..7423 -> rows 924..927)
__global__ void zero_pad2(f16* __restrict__ feats2) {
    int idx = blockIdx.x * 256 + threadIdx.x;
    u32* dst = (u32*)(feats2 + (size_t)(CCH * 14) * ROWE);
    if (idx < (4 * ROWE * 2) / 16)
        *(u32x4*)(dst + idx * 4) = (u32x4){0u, 0u, 0u, 0u};
}

// convert fw1 (1936 x 7128 f32) -> padded f16 (2048 x 7424) with per-c pad
__global__ void cvt_fw1(const float* __restrict__ fw1, f16* __restrict__ dst) {
    int n = blockIdx.y;
    int kp = blockIdx.x * 256 + threadIdx.x;
    if (kp >= KP2) return;
    int c2 = kp / FPC, f = kp - c2 * FPC;
    float v = 0.f;
    if (n < NOUT && kp < KF2 && f < 108)
        v = fw1[(size_t)n * KFEAT + c2 * 108 + f];
    dst[(size_t)n * KP2 + kp] = (f16)v;
}

// ---------------------------------------------------------------- FC1 GEMM
// A in feats2 blocked layout; Bw [n][KP2]; H = relu(A.Bw^T + fb1) f16 [m][NPAD]
__global__ __launch_bounds__(256) void fc1_gemm(
    const f16* __restrict__ A, const f16* __restrict__ Bw,
    const float* __restrict__ fb1, f16* __restrict__ H) {
    __shared__ f16 lds_a[128 * 32];
    __shared__ f16 lds_b[128 * 32];
    const int tid = threadIdx.x;
    const int bm = blockIdx.x;  // 32 tiles of M
    const int bn = blockIdx.y;  // 16 tiles of N
    const int wid = tid >> 6, lane = tid & 63;
    const int wm = wid >> 1, wn = wid & 1;

    f32x4 acc[4][4];
#pragma unroll
    for (int i = 0; i < 4; ++i)
#pragma unroll
        for (int j = 0; j < 4; ++j) acc[i][j] = (f32x4){0.f, 0.f, 0.f, 0.f};

    const f16* Bbase = Bw + (size_t)bn * 128 * KP2;
    const int l15 = lane & 15, lhi = lane >> 4;

    const int flat0 = tid, flat1 = 256 + tid;
    const int row0 = flat0 >> 2, kc0 = flat0 & 3;
    const int row1 = flat1 >> 2, kc1 = flat1 & 3;

    for (int k0 = 0; k0 < KP2; k0 += 32) {
        __syncthreads();
        gload_lds16(A + (size_t)((k0 >> 3) + kc0) * ROWE + (size_t)(bm * 128 + row0) * 8,
                    (char*)lds_a + flat0 * 16);
        gload_lds16(A + (size_t)((k0 >> 3) + kc1) * ROWE + (size_t)(bm * 128 + row1) * 8,
                    (char*)lds_a + flat1 * 16);
        gload_lds16(Bbase + (size_t)row0 * KP2 + k0 + kc0 * 8, (char*)lds_b + flat0 * 16);
        gload_lds16(Bbase + (size_t)row1 * KP2 + k0 + kc1 * 8, (char*)lds_b + flat1 * 16);
        __syncthreads();

        f16x8 af[4], bf[4];
#pragma unroll
        for (int i = 0; i < 4; ++i) {
            int m = wm * 64 + i * 16 + l15;
            af[i] = *(const f16x8*)(lds_a + m * 32 + lhi * 8);
            int n = wn * 64 + i * 16 + l15;
            bf[i] = *(const f16x8*)(lds_b + n * 32 + lhi * 8);
        }
#pragma unroll
        for (int i = 0; i < 4; ++i)
#pragma unroll
            for (int j = 0; j < 4; ++j)
                acc[i][j] = __builtin_amdgcn_mfma_f32_16x16x32_f16(af[i], bf[j], acc[i][j], 0, 0, 0);
    }

    // epilogue: C/D layout col = lane&15, row = (lane>>4)*4 + r
#pragma unroll
    for (int i = 0; i < 4; ++i) {
#pragma unroll
        for (int j = 0; j < 4; ++j) {
            int n = bn * 128 + wn * 64 + j * 16 + l15;
            float bias = (n < NOUT) ? fb1[n] : 0.f;
#pragma unroll
            for (int r = 0; r < 4; ++r) {
                int m = bm * 128 + wm * 64 + i * 16 + lhi * 4 + r;
                float v = acc[i][j][r] + bias;
                H[(size_t)m * NPAD + n] = (f16)fmaxf(v, 0.f);
            }
        }
    }
}

// ---------------------------------------------------------------- FC2
__global__ __launch_bounds__(64) void fc2_kernel(const f16* __restrict__ H,
                                                 const float* __restrict__ fw2,
                                                 const float* __restrict__ fb2,
                                                 float* __restrict__ out) {
    const int b = blockIdx.x;
    const int t = threadIdx.x;
    const f16* hb = H + (size_t)b * NPAD;
    float acc[14];
#pragma unroll
    for (int o = 0; o < 14; ++o) acc[o] = 0.f;
    for (int k = t; k < NOUT; k += 64) {
        float hv = (float)hb[k];
#pragma unroll
        for (int o = 0; o < 14; ++o) acc[o] += hv * fw2[o * NOUT + k];
    }
#pragma unroll
    for (int o = 0; o < 14; ++o) {
        float v = acc[o];
#pragma unroll
        for (int off = 32; off > 0; off >>= 1) v += __shfl_down(v, off, 64);
        if (t == 0) out[b * 14 + o] = v + fb2[o];
    }
}

// ---------------------------------------------------------------- launcher
extern "C" void kernel_launch(void* const* d_in, const int* in_sizes, int n_in,
                              void* d_out, int out_size, void* d_ws, size_t ws_size,
                              hipStream_t stream) {
    const float* x   = (const float*)d_in[0];
    const float* hw1 = (const float*)d_in[1];
    const float* hb1 = (const float*)d_in[2];
    const float* hw2 = (const float*)d_in[3];
    const float* hb2 = (const float*)d_in[4];
    const float* hw3 = (const float*)d_in[5];
    const float* hb3 = (const float*)d_in[6];
    const float* lw1 = (const float*)d_in[7];
    const float* lb1 = (const float*)d_in[8];
    const float* lw2 = (const float*)d_in[9];
    const float* lb2 = (const float*)d_in[10];
    const float* lw3 = (const float*)d_in[11];
    const float* lb3 = (const float*)d_in[12];
    const float* fw1 = (const float*)d_in[13];
    const float* fb1 = (const float*)d_in[14];
    const float* fw2 = (const float*)d_in[15];
    const float* fb2 = (const float*)d_in[16];

    // workspace layout (xT and h alias: disjoint lifetimes)
    f16* feats2 = (f16*)d_ws;                               // 928*32768 f16 = 60.8 MB
    f16* fw1H   = feats2 + (size_t)NCH2 * ROWE;             // 2048*7424 f16 = 30.4 MB
    f16* xT     = fw1H + (size_t)NPAD * KP2;                // 6600*4096 f16 = 54.1 MB
    f16* h      = xT;                                       // 4096*2048 f16 = 16.8 MB (aliases xT)

    transpose_x<<<dim3((LC + 31) / 32, BSZ / 32), 256, 0, stream>>>(x, xT);
    feats_kernel<<<dim3(CCH, BSZ / 256), 256, 0, stream>>>(
        xT, hw1, hb1, hw2, hb2, hw3, hb3, lw1, lb1, lw2, lb2, lw3, lb3, feats2);
    zero_pad2<<<dim3(64), 256, 0, stream>>>(feats2);
    cvt_fw1<<<dim3((KP2 + 255) / 256, NPAD), 256, 0, stream>>>(fw1, fw1H);
    fc1_gemm<<<dim3(BSZ / 128, NPAD / 128), 256, 0, stream>>>(feats2, fw1H, fb1, h);
    fc2_kernel<<<dim3(BSZ), 64, 0, stream>>>(h, fw2, fb2, (float*)d_out);
}

// Round 6
// 889.282 us; speedup vs baseline: 1.3954x; 1.1528x over previous
//
#include <hip/hip_runtime.h>

typedef _Float16 f16;
typedef _Float16 f16x8 __attribute__((ext_vector_type(8)));
typedef float    f32x4 __attribute__((ext_vector_type(4)));
typedef unsigned int u32;
typedef u32 u32x4 __attribute__((ext_vector_type(4)));

#define CCH 66
#define LLEN 100
#define BSZ 4096
#define NPAD 2048
#define NOUT 1936
#define KFEAT 7128
#define FPC 112                 // padded features per channel (108 real + 4 zero)
#define KF2 (CCH * FPC)         // 7392
#define KP2 7424                // KF2 padded to x32
#define NCH2 (KP2 / 8)          // 928 chunk-rows in feats2
#define ROWE (BSZ * 8)          // f16 elements per chunk-row (32768)
#define XSTR (CCH * BSZ)        // element stride between successive l in xT
#define LC (LLEN * CCH)
#define OSTR 25                 // obuf row stride in u32 (odd -> conflict-free, 0 measured)

// ---------------------------------------------------------------- async G->LDS
typedef __attribute__((address_space(1))) const u32 gu32;
typedef __attribute__((address_space(3))) u32 lu32;

__device__ __forceinline__ void gload_lds16(const void* g, void* l) {
    __builtin_amdgcn_global_load_lds((gu32*)g, (lu32*)l, 16, 0, 0);
}

__device__ __forceinline__ u32 pk(f16 lo, f16 hi) {
    unsigned short a = __builtin_bit_cast(unsigned short, lo);
    unsigned short b = __builtin_bit_cast(unsigned short, hi);
    return (u32)a | ((u32)b << 16);
}

// ---------------------------------------------------------------- x transpose
// x [B][L*C] f32  ->  xT [L*C][B] f16   (element (l,c) row index = l*66+c)
__global__ __launch_bounds__(256) void transpose_x(const float* __restrict__ x,
                                                   f16* __restrict__ xT) {
    __shared__ float tile[32][33];
    const int m0 = blockIdx.x * 32;           // lc index
    const int b0 = blockIdx.y * 32;           // batch index
    const int tx = threadIdx.x & 31, ty = threadIdx.x >> 5;  // 32 x 8
#pragma unroll
    for (int i = 0; i < 32; i += 8) {
        int m = m0 + tx, b = b0 + ty + i;
        tile[ty + i][tx] = (m < LC) ? x[(size_t)b * LC + m] : 0.f;
    }
    __syncthreads();
#pragma unroll
    for (int i = 0; i < 32; i += 8) {
        int m = m0 + ty + i, b = b0 + tx;
        if (m < LC) xT[(size_t)m * BSZ + b] = (f16)tile[tx][ty + i];
    }
}

// ---------------------------------------------------------------- feature pipeline
__device__ __forceinline__ float ldx(const f16* __restrict__ xb, int u) {
    return (float)xb[(size_t)u * XSTR];
}

// paired hp1 columns idx, idx+1 from one shared window of K+3 x values
template<int K>
__device__ __forceinline__ void hp1_pair(const f16* __restrict__ xb, int idx,
                                         const float* __restrict__ w1,
                                         const float* __restrict__ b1,
                                         float colA[8], float colB[8]) {
    constexpr int P = K / 2;
    constexpr int W = K + 3;
    float xv[W];
#pragma unroll
    for (int j = 0; j < W; ++j) {
        int u = 2 * idx - P + j;
        xv[j] = (u >= 0 && u < LLEN) ? ldx(xb, u) : 0.f;
    }
    const bool vA = (idx < 50), vB = (idx + 1 < 50);
#pragma unroll
    for (int ic = 0; ic < 8; ++ic) {
        float a0 = b1[ic], a1 = b1[ic], a2 = b1[ic], a3 = b1[ic];
#pragma unroll
        for (int k = 0; k < K; ++k) {
            float w = w1[ic * K + k];
            a0 += w * xv[k];
            a1 += w * xv[k + 1];
            a2 += w * xv[k + 2];
            a3 += w * xv[k + 3];
        }
        colA[ic] = vA ? 0.5f * (fmaxf(a0, 0.f) + fmaxf(a1, 0.f)) : 0.f;
        colB[ic] = vB ? 0.5f * (fmaxf(a2, 0.f) + fmaxf(a3, 0.f)) : 0.f;
    }
}

// Rolled-loop branch (R2-proven body; do NOT unroll the s-loop — R4/R5 showed
// full/partial unroll causes catastrophic scratch spill). Packed outputs
// out[oc][t] (f16) go to LDS row orow as u32 word oc*6 + t/2.
template<int K>
__device__ __forceinline__ void run_branch(const f16* __restrict__ xb,
                                           const float* __restrict__ w1, const float* __restrict__ b1,
                                           const float* __restrict__ w2, const float* __restrict__ b2,
                                           const float* __restrict__ w3, const float* __restrict__ b3,
                                           u32* __restrict__ orow) {
    constexpr int P = K / 2;
    float W1[8][K + 1];
    float W2[4][K];
#pragma unroll
    for (int ic = 0; ic < 8; ++ic)
#pragma unroll
        for (int j = 0; j <= K; ++j) W1[ic][j] = 0.f;
#pragma unroll
    for (int oc = 0; oc < 4; ++oc)
#pragma unroll
        for (int j = 0; j < K; ++j) W2[oc][j] = 0.f;

    // prologue: W1[.][P+idx] = hp1[idx] for idx = 0..P+1
#pragma unroll
    for (int idx = 0; idx <= P + 1; idx += 2) {
        float cA[8], cB[8];
        hp1_pair<K>(xb, idx, w1, b1, cA, cB);
#pragma unroll
        for (int ic = 0; ic < 8; ++ic) {
            W1[ic][P + idx] = cA[ic];
            if (idx + 1 <= P + 1) W1[ic][P + idx + 1] = cB[ic];
        }
    }

    float pacc[4] = {0.f, 0.f, 0.f, 0.f};
    f16 pend[4] = {(f16)0.f, (f16)0.f, (f16)0.f, (f16)0.f};
    const int SMAX = 23 + P;  // last y3 position p = 23
    for (int s = 0; s <= SMAX; ++s) {
        // hp2[s] from y2 at 2s, 2s+1
        float h2col[4];
        if (s <= 24) {
#pragma unroll
            for (int oc = 0; oc < 4; ++oc) {
                float ya = b2[oc], yb = b2[oc];
#pragma unroll
                for (int ic = 0; ic < 8; ++ic)
#pragma unroll
                    for (int k = 0; k < K; ++k) {
                        float w = w2[(oc * 8 + ic) * K + k];
                        ya += w * W1[ic][k];
                        yb += w * W1[ic][k + 1];
                    }
                h2col[oc] = 0.5f * (fmaxf(ya, 0.f) + fmaxf(yb, 0.f));
            }
        } else {
#pragma unroll
            for (int oc = 0; oc < 4; ++oc) h2col[oc] = 0.f;
        }
        // shift W2, append hp2[s]
#pragma unroll
        for (int oc = 0; oc < 4; ++oc) {
#pragma unroll
            for (int j = 0; j < K - 1; ++j) W2[oc][j] = W2[oc][j + 1];
            W2[oc][K - 1] = h2col[oc];
        }
        // y3 at p = s - P; pool pairs -> packed output word at t = p>>1 pairs
        int p = s - P;
        if (p >= 0) {
            float y3[4];
#pragma unroll
            for (int oc = 0; oc < 4; ++oc) {
                float y = b3[oc];
#pragma unroll
                for (int ic = 0; ic < 4; ++ic)
#pragma unroll
                    for (int k = 0; k < K; ++k)
                        y += w3[(oc * 4 + ic) * K + k] * W2[ic][k];
                y3[oc] = fmaxf(y, 0.f);
            }
            if ((p & 1) == 0) {
#pragma unroll
                for (int oc = 0; oc < 4; ++oc) pacc[oc] = y3[oc];
            } else {
                int t = p >> 1;
                if ((t & 1) == 0) {
#pragma unroll
                    for (int oc = 0; oc < 4; ++oc)
                        pend[oc] = (f16)(0.5f * (pacc[oc] + y3[oc]));
                } else {
#pragma unroll
                    for (int oc = 0; oc < 4; ++oc)
                        orow[oc * 6 + (t >> 1)] = pk(pend[oc], (f16)(0.5f * (pacc[oc] + y3[oc])));
                }
            }
        }
        // advance W1 by 2 columns
        if (s < SMAX) {
#pragma unroll
            for (int ic = 0; ic < 8; ++ic)
#pragma unroll
                for (int j = 0; j < K - 1; ++j) W1[ic][j] = W1[ic][j + 2];
            float colA[8], colB[8];
            hp1_pair<K>(xb, 2 * s + P + 2, w1, b1, colA, colB);
#pragma unroll
            for (int ic = 0; ic < 8; ++ic) {
                W1[ic][K - 1] = colA[ic];
                W1[ic][K]     = colB[ic];
            }
        }
    }
}

// feats2 blocked layout: element (b, k = c*112 + f) lives at
//   feats2[(c*14 + (f>>3)) * ROWE + b*8 + (f&7)]
__global__ __launch_bounds__(256, 2) void feats_kernel(
    const f16* __restrict__ xT,
    const float* __restrict__ hw1, const float* __restrict__ hb1,
    const float* __restrict__ hw2, const float* __restrict__ hb2,
    const float* __restrict__ hw3, const float* __restrict__ hb3,
    const float* __restrict__ lw1, const float* __restrict__ lb1,
    const float* __restrict__ lw2, const float* __restrict__ lb2,
    const float* __restrict__ lw3, const float* __restrict__ lb3,
    f16* __restrict__ feats2) {
    __shared__ u32 obufw[256 * OSTR];   // 25.6 KB -> up to 6 blocks/CU
    const int c = blockIdx.x;
    const int tid = threadIdx.x;
    const int b = blockIdx.y * 256 + tid;
    const f16* xb = xT + (size_t)c * BSZ + b;  // element l at xb[l*XSTR]
    u32* orow = obufw + tid * OSTR;
    u32* dst = (u32*)feats2 + (size_t)c * 14 * (ROWE / 2) + (size_t)b * 4;

    // ---- high branch (K=7) -> chunks 0..5
    run_branch<7>(xb, hw1 + c * 56, hb1 + c * 8, hw2 + c * 224, hb2 + c * 4,
                  hw3 + c * 112, hb3 + c * 4, orow);
    {
        u32 v[24];
#pragma unroll
        for (int j = 0; j < 24; ++j) v[j] = orow[j];   // same-thread RAW, no barrier
#pragma unroll
        for (int ch = 0; ch < 6; ++ch)
            *(u32x4*)(dst + (size_t)ch * (ROWE / 2)) =
                (u32x4){v[ch * 4], v[ch * 4 + 1], v[ch * 4 + 2], v[ch * 4 + 3]};
    }

    // ---- low branch (K=3) -> chunks 6..11 (reuses orow)
    run_branch<3>(xb, lw1 + c * 24, lb1 + c * 8, lw2 + c * 96, lb2 + c * 4,
                  lw3 + c * 48, lb3 + c * 4, orow);
    {
        u32 v[24];
#pragma unroll
        for (int j = 0; j < 24; ++j) v[j] = orow[j];
#pragma unroll
        for (int ch = 0; ch < 6; ++ch)
            *(u32x4*)(dst + (size_t)(6 + ch) * (ROWE / 2)) =
                (u32x4){v[ch * 4], v[ch * 4 + 1], v[ch * 4 + 2], v[ch * 4 + 3]};
    }

    // ---- residual pooling -> chunks 12..13 (registers only, static indices)
    u32 orr[6];
#pragma unroll
    for (int t2 = 0; t2 < 6; ++t2) {
        float s0 = 0.f, s1 = 0.f;
#pragma unroll
        for (int j = 0; j < 8; ++j) {
            s0 += ldx(xb, 16 * t2 + j);
            s1 += ldx(xb, 16 * t2 + 8 + j);
        }
        orr[t2] = pk((f16)(s0 * 0.125f), (f16)(s1 * 0.125f));
    }
    *(u32x4*)(dst + (size_t)12 * (ROWE / 2)) = (u32x4){orr[0], orr[1], orr[2], orr[3]};
    *(u32x4*)(dst + (size_t)13 * (ROWE / 2)) = (u32x4){orr[4], orr[5], 0u, 0u};
}

// zero the pad chunk-rows (k = 7392..7423 -> rows 924..927)
__global__ void zero_pad2(f16* __restrict__ feats2) {
    int idx = blockIdx.x * 256 + threadIdx.x;
    u32* dst = (u32*)(feats2 + (size_t)(CCH * 14) * ROWE);
    if (idx < (4 * ROWE * 2) / 16)
        *(u32x4*)(dst + idx * 4) = (u32x4){0u, 0u, 0u, 0u};
}

// convert fw1 (1936 x 7128 f32) -> padded f16 (2048 x 7424) with per-c pad
__global__ void cvt_fw1(const float* __restrict__ fw1, f16* __restrict__ dst) {
    int n = blockIdx.y;
    int kp = blockIdx.x * 256 + threadIdx.x;
    if (kp >= KP2) return;
    int c2 = kp / FPC, f = kp - c2 * FPC;
    float v = 0.f;
    if (n < NOUT && kp < KF2 && f < 108)
        v = fw1[(size_t)n * KFEAT + c2 * 108 + f];
    dst[(size_t)n * KP2 + kp] = (f16)v;
}

// ---------------------------------------------------------------- FC1 GEMM
// A in feats2 blocked layout; Bw [n][KP2]; H = relu(A.Bw^T + fb1) f16 [m][NPAD]
__global__ __launch_bounds__(256) void fc1_gemm(
    const f16* __restrict__ A, const f16* __restrict__ Bw,
    const float* __restrict__ fb1, f16* __restrict__ H) {
    __shared__ f16 lds_a[128 * 32];
    __shared__ f16 lds_b[128 * 32];
    const int tid = threadIdx.x;
    const int bm = blockIdx.x;  // 32 tiles of M
    const int bn = blockIdx.y;  // 16 tiles of N
    const int wid = tid >> 6, lane = tid & 63;
    const int wm = wid >> 1, wn = wid & 1;

    f32x4 acc[4][4];
#pragma unroll
    for (int i = 0; i < 4; ++i)
#pragma unroll
        for (int j = 0; j < 4; ++j) acc[i][j] = (f32x4){0.f, 0.f, 0.f, 0.f};

    const f16* Bbase = Bw + (size_t)bn * 128 * KP2;
    const int l15 = lane & 15, lhi = lane >> 4;

    const int flat0 = tid, flat1 = 256 + tid;
    const int row0 = flat0 >> 2, kc0 = flat0 & 3;
    const int row1 = flat1 >> 2, kc1 = flat1 & 3;

    for (int k0 = 0; k0 < KP2; k0 += 32) {
        __syncthreads();
        gload_lds16(A + (size_t)((k0 >> 3) + kc0) * ROWE + (size_t)(bm * 128 + row0) * 8,
                    (char*)lds_a + flat0 * 16);
        gload_lds16(A + (size_t)((k0 >> 3) + kc1) * ROWE + (size_t)(bm * 128 + row1) * 8,
                    (char*)lds_a + flat1 * 16);
        gload_lds16(Bbase + (size_t)row0 * KP2 + k0 + kc0 * 8, (char*)lds_b + flat0 * 16);
        gload_lds16(Bbase + (size_t)row1 * KP2 + k0 + kc1 * 8, (char*)lds_b + flat1 * 16);
        __syncthreads();

        f16x8 af[4], bf[4];
#pragma unroll
        for (int i = 0; i < 4; ++i) {
            int m = wm * 64 + i * 16 + l15;
            af[i] = *(const f16x8*)(lds_a + m * 32 + lhi * 8);
            int n = wn * 64 + i * 16 + l15;
            bf[i] = *(const f16x8*)(lds_b + n * 32 + lhi * 8);
        }
#pragma unroll
        for (int i = 0; i < 4; ++i)
#pragma unroll
            for (int j = 0; j < 4; ++j)
                acc[i][j] = __builtin_amdgcn_mfma_f32_16x16x32_f16(af[i], bf[j], acc[i][j], 0, 0, 0);
    }

    // epilogue: C/D layout col = lane&15, row = (lane>>4)*4 + r
#pragma unroll
    for (int i = 0; i < 4; ++i) {
#pragma unroll
        for (int j = 0; j < 4; ++j) {
            int n = bn * 128 + wn * 64 + j * 16 + l15;
            float bias = (n < NOUT) ? fb1[n] : 0.f;
#pragma unroll
            for (int r = 0; r < 4; ++r) {
                int m = bm * 128 + wm * 64 + i * 16 + lhi * 4 + r;
                float v = acc[i][j][r] + bias;
                H[(size_t)m * NPAD + n] = (f16)fmaxf(v, 0.f);
            }
        }
    }
}

// ---------------------------------------------------------------- FC2
__global__ __launch_bounds__(64) void fc2_kernel(const f16* __restrict__ H,
                                                 const float* __restrict__ fw2,
                                                 const float* __restrict__ fb2,
                                                 float* __restrict__ out) {
    const int b = blockIdx.x;
    const int t = threadIdx.x;
    const f16* hb = H + (size_t)b * NPAD;
    float acc[14];
#pragma unroll
    for (int o = 0; o < 14; ++o) acc[o] = 0.f;
    for (int k = t; k < NOUT; k += 64) {
        float hv = (float)hb[k];
#pragma unroll
        for (int o = 0; o < 14; ++o) acc[o] += hv * fw2[o * NOUT + k];
    }
#pragma unroll
    for (int o = 0; o < 14; ++o) {
        float v = acc[o];
#pragma unroll
        for (int off = 32; off > 0; off >>= 1) v += __shfl_down(v, off, 64);
        if (t == 0) out[b * 14 + o] = v + fb2[o];
    }
}

// ---------------------------------------------------------------- launcher
extern "C" void kernel_launch(void* const* d_in, const int* in_sizes, int n_in,
                              void* d_out, int out_size, void* d_ws, size_t ws_size,
                              hipStream_t stream) {
    const float* x   = (const float*)d_in[0];
    const float* hw1 = (const float*)d_in[1];
    const float* hb1 = (const float*)d_in[2];
    const float* hw2 = (const float*)d_in[3];
    const float* hb2 = (const float*)d_in[4];
    const float* hw3 = (const float*)d_in[5];
    const float* hb3 = (const float*)d_in[6];
    const float* lw1 = (const float*)d_in[7];
    const float* lb1 = (const float*)d_in[8];
    const float* lw2 = (const float*)d_in[9];
    const float* lb2 = (const float*)d_in[10];
    const float* lw3 = (const float*)d_in[11];
    const float* lb3 = (const float*)d_in[12];
    const float* fw1 = (const float*)d_in[13];
    const float* fb1 = (const float*)d_in[14];
    const float* fw2 = (const float*)d_in[15];
    const float* fb2 = (const float*)d_in[16];

    // workspace layout (xT and h alias: disjoint lifetimes)
    f16* feats2 = (f16*)d_ws;                               // 928*32768 f16 = 60.8 MB
    f16* fw1H   = feats2 + (size_t)NCH2 * ROWE;             // 2048*7424 f16 = 30.4 MB
    f16* xT     = fw1H + (size_t)NPAD * KP2;                // 6600*4096 f16 = 54.1 MB
    f16* h      = xT;                                       // 4096*2048 f16 = 16.8 MB (aliases xT)

    transpose_x<<<dim3((LC + 31) / 32, BSZ / 32), 256, 0, stream>>>(x, xT);
    feats_kernel<<<dim3(CCH, BSZ / 256), 256, 0, stream>>>(
        xT, hw1, hb1, hw2, hb2, hw3, hb3, lw1, lb1, lw2, lb2, lw3, lb3, feats2);
    zero_pad2<<<dim3(64), 256, 0, stream>>>(feats2);
    cvt_fw1<<<dim3((KP2 + 255) / 256, NPAD), 256, 0, stream>>>(fw1, fw1H);
    fc1_gemm<<<dim3(BSZ / 128, NPAD / 128), 256, 0, stream>>>(feats2, fw1H, fb1, h);
    fc2_kernel<<<dim3(BSZ), 64, 0, stream>>>(h, fw2, fb2, (float*)d_out);
}

// Round 7
// 783.177 us; speedup vs baseline: 1.5844x; 1.1355x over previous
//
#include <hip/hip_runtime.h>

typedef _Float16 f16;
typedef _Float16 h2 __attribute__((ext_vector_type(2)));
typedef _Float16 f16x8 __attribute__((ext_vector_type(8)));
typedef float    f32x4 __attribute__((ext_vector_type(4)));
typedef unsigned int u32;
typedef u32 u32x2 __attribute__((ext_vector_type(2)));
typedef u32 u32x4 __attribute__((ext_vector_type(4)));

#define CCH 66
#define LLEN 100
#define BSZ 4096
#define NPAD 2048
#define NOUT 1936
#define KFEAT 7128
#define FPC 112                 // padded features per channel (108 real + 4 zero)
#define KF2 (CCH * FPC)         // 7392
#define KP2 7424                // KF2 padded to x32
#define NCH2 (KP2 / 8)          // 928 chunk-rows in feats2
#define ROWE (BSZ * 8)          // f16 elements per chunk-row (32768)
#define LC (LLEN * CCH)
#define OSTR 25                 // obuf row stride in u32 (odd -> conflict-free, 0 measured R6)
#define XPW 52                  // u32 pair-rows per channel (50 data + 2 zero halo)
#define CWS 512                 // packed-weight stride per channel (u32)

// ---------------------------------------------------------------- async G->LDS
typedef __attribute__((address_space(1))) const u32 gu32;
typedef __attribute__((address_space(3))) u32 lu32;

__device__ __forceinline__ void gload_lds16(const void* g, void* l) {
    __builtin_amdgcn_global_load_lds((gu32*)g, (lu32*)l, 16, 0, 0);
}

// ---------------------------------------------------------------- h2 helpers
__device__ __forceinline__ h2  uh(u32 v) { return __builtin_bit_cast(h2, v); }
__device__ __forceinline__ u32 hu(h2 v)  { return __builtin_bit_cast(u32, v); }
__device__ __forceinline__ h2  pkfma(h2 a, h2 b, h2 c) { return __builtin_elementwise_fma(a, b, c); }
__device__ __forceinline__ h2  pkmax0(h2 a) { h2 z = (h2)(_Float16)0.f; return __builtin_elementwise_max(a, z); }

// ---------------------------------------------------------------- x transpose
// x [B][L*C] f32  ->  xT [L*C][B] f16
__global__ __launch_bounds__(256) void transpose_x(const float* __restrict__ x,
                                                   f16* __restrict__ xT) {
    __shared__ float tile[32][33];
    const int m0 = blockIdx.x * 32;
    const int b0 = blockIdx.y * 32;
    const int tx = threadIdx.x & 31, ty = threadIdx.x >> 5;
#pragma unroll
    for (int i = 0; i < 32; i += 8) {
        int m = m0 + tx, b = b0 + ty + i;
        tile[ty + i][tx] = (m < LC) ? x[(size_t)b * LC + m] : 0.f;
    }
    __syncthreads();
#pragma unroll
    for (int i = 0; i < 32; i += 8) {
        int m = m0 + ty + i, b = b0 + tx;
        if (m < LC) xT[(size_t)m * BSZ + b] = (f16)tile[tx][ty + i];
    }
}

// xT -> xP[c][w][b] u32 = (x[2w], x[2w+1]) f16 pair; w=50,51 zero halo
__global__ __launch_bounds__(256) void pack_x(const f16* __restrict__ xT,
                                              u32* __restrict__ xP) {
    const int c = blockIdx.x, w = blockIdx.y;
    const int b = blockIdx.z * 256 + threadIdx.x;
    u32 v = 0u;
    if (w < 50) {
        f16 lo = xT[(size_t)(2 * w * CCH + c) * BSZ + b];
        f16 hi = xT[(size_t)((2 * w + 1) * CCH + c) * BSZ + b];
        v = hu((h2){lo, hi});
    }
    xP[((size_t)c * XPW + w) * BSZ + b] = v;
}

// ---------------------------------------------------------------- packed weights
// per-c layout (u32): high @0: w1d[56] b1d[8] w2d[224] b2d[4] w3p[56] b3p[2]
//                      low @350: w1d[24] b1d[8] w2d[96]  b2d[4] w3p[24] b3p[2]
__device__ __forceinline__ u32 dupf(float v) {
    _Float16 h = (_Float16)v; return hu((h2){h, h});
}
__device__ __forceinline__ u32 pk2f(float a, float b) {
    return hu((h2){(_Float16)a, (_Float16)b});
}

__global__ __launch_bounds__(64) void prep_w(
    const float* __restrict__ hw1, const float* __restrict__ hb1,
    const float* __restrict__ hw2, const float* __restrict__ hb2,
    const float* __restrict__ hw3, const float* __restrict__ hb3,
    const float* __restrict__ lw1, const float* __restrict__ lb1,
    const float* __restrict__ lw2, const float* __restrict__ lb2,
    const float* __restrict__ lw3, const float* __restrict__ lb3,
    u32* __restrict__ wpk) {
    const int c = blockIdx.x, t = threadIdx.x;
    u32* wb = wpk + c * CWS;
    for (int i = t; i < 56; i += 64) wb[i] = dupf(hw1[c * 56 + i]);
    if (t < 8)  wb[56 + t] = dupf(hb1[c * 8 + t]);
    for (int i = t; i < 224; i += 64) wb[64 + i] = dupf(hw2[c * 224 + i]);
    if (t < 4)  wb[288 + t] = dupf(hb2[c * 4 + t]);
    for (int i = t; i < 56; i += 64) {
        int pr = i / 28, j = i - pr * 28;
        wb[292 + i] = pk2f(hw3[c * 112 + 2 * pr * 28 + j], hw3[c * 112 + (2 * pr + 1) * 28 + j]);
    }
    if (t < 2)  wb[348 + t] = pk2f(hb3[c * 4 + 2 * t], hb3[c * 4 + 2 * t + 1]);
    for (int i = t; i < 24; i += 64) wb[350 + i] = dupf(lw1[c * 24 + i]);
    if (t < 8)  wb[374 + t] = dupf(lb1[c * 8 + t]);
    for (int i = t; i < 96; i += 64) wb[382 + i] = dupf(lw2[c * 96 + i]);
    if (t < 4)  wb[478 + t] = dupf(lb2[c * 4 + t]);
    for (int i = t; i < 24; i += 64) {
        int pr = i / 12, j = i - pr * 12;
        wb[482 + i] = pk2f(lw3[c * 48 + 2 * pr * 12 + j], lw3[c * 48 + (2 * pr + 1) * 12 + j]);
    }
    if (t < 2)  wb[506 + t] = pk2f(lb3[c * 4 + 2 * t], lb3[c * 4 + 2 * t + 1]);
}

// ---------------------------------------------------------------- feature pipeline (pk-f16)
// hp1 core: PX[j] = packed x pair starting at u0+j; emits np[ic] = (colA,colB)
template<int K>
__device__ __forceinline__ void hp1_core(const u32* PX, const u32* __restrict__ w1d,
                                         const u32* __restrict__ b1d, u32 msk, u32 np[8]) {
#pragma unroll
    for (int ic = 0; ic < 8; ++ic) {
        h2 bb = uh(b1d[ic]);
        h2 AL = bb, AH = bb;
#pragma unroll
        for (int k = 0; k < K; ++k) {
            h2 w = uh(w1d[ic * K + k]);
            AL = pkfma(w, uh(PX[k]), AL);
            AH = pkfma(w, uh(PX[k + 2]), AH);
        }
        AL = pkmax0(AL); AH = pkmax0(AH);
        _Float16 cA = (_Float16)0.5f * (AL.x + AL.y);
        _Float16 cB = (_Float16)0.5f * (AH.x + AH.y);
        np[ic] = hu((h2){cA, cB}) & msk;
    }
}

// runtime-idx hp1 (s-loop; idx >= 2 so all LDS rows >= 0; out-of-range rows land
// in obuf garbage and are zeroed by the unconditional mask AND — NaN-safe)
template<int K>
__device__ __forceinline__ void hp1_run(const u32* __restrict__ xlt, int idx,
                                        const u32* w1d, const u32* b1d, u32 np[8]) {
    constexpr int P = K / 2;
    constexpr int NA = (K + 5) / 2;     // 6 (K=7), 4 (K=3)
    const int w0 = idx - (P + 1) / 2;
    const u32* base = xlt + w0 * 256;
    u32 A[NA];
#pragma unroll
    for (int j = 0; j < NA; ++j) A[j] = base[j * 256];
    u32 PX[K + 2];
#pragma unroll
    for (int j = 0; j < K + 2; ++j)
        PX[j] = (j & 1) ? A[(j + 1) / 2]
                        : __builtin_amdgcn_alignbit(A[j / 2 + 1], A[j / 2], 16);
    u32 m = ((idx < 50) ? 0xFFFFu : 0u) | ((idx + 1 < 50) ? 0xFFFF0000u : 0u);
    hp1_core<K>(PX, w1d, b1d, m, np);
}

// compile-time-idx hp1 for the prologue (handles u<0 as zeros; all folds)
template<int K, int IDX>
__device__ __forceinline__ void hp1_edge(const u32* __restrict__ xlt,
                                         const u32* w1d, const u32* b1d, u32 np[8]) {
    constexpr int P = K / 2;
    u32 PX[K + 2];
#pragma unroll
    for (int j = 0; j < K + 2; ++j) {
        int u = 2 * IDX - P + j;
        u32 v;
        if (u < -1)      v = 0u;
        else if (u == -1) v = xlt[0] << 16;   // (x[-1]=0, x[0])
        else if (u & 1)  v = __builtin_amdgcn_alignbit(xlt[((u + 1) / 2) * 256],
                                                       xlt[((u - 1) / 2) * 256], 16);
        else             v = xlt[(u / 2) * 256];
        PX[j] = v;
    }
    hp1_core<K>(PX, w1d, b1d, 0xFFFFFFFFu, np);
}

// Full branch, packed-f16. W1p[ic][j] = (hp1 col 2j, col 2j+1); W2d holds
// duplicated hp2 history. Rolled s-loop (R4/R5: do NOT unroll).
template<int K>
__device__ __forceinline__ void run_branch_pk(const u32* __restrict__ xlt,
                                              const u32* __restrict__ wb,
                                              u32* __restrict__ orow) {
    constexpr int P = K / 2;
    constexpr int NW1 = (K + 1) / 2;
    const u32* w1d = wb;
    const u32* b1d = wb + 8 * K;
    const u32* w2d = b1d + 8;
    const u32* b2d = w2d + 32 * K;
    const u32* w3p = b2d + 4;
    const u32* b3p = w3p + 8 * K;

    u32 W1p[8][NW1];
    u32 W2d[4][K];
#pragma unroll
    for (int ic = 0; ic < 8; ++ic)
#pragma unroll
        for (int j = 0; j < NW1; ++j) W1p[ic][j] = 0u;
#pragma unroll
    for (int oc = 0; oc < 4; ++oc)
#pragma unroll
        for (int k = 0; k < K; ++k) W2d[oc][k] = 0u;

    // prologue: fill W1p so cols j hold hp1[-P+j] (zeros for negative)
    {
        u32 np[8];
        if (K == 7) {
            hp1_edge<K, 0>(xlt, w1d, b1d, np);
#pragma unroll
            for (int ic = 0; ic < 8; ++ic) W1p[ic][1] = np[ic] << 16;  // (0, c0)
            hp1_edge<K, 1>(xlt, w1d, b1d, np);
#pragma unroll
            for (int ic = 0; ic < 8; ++ic) W1p[ic][2] = np[ic];        // (c1, c2)
            hp1_edge<K, 3>(xlt, w1d, b1d, np);
#pragma unroll
            for (int ic = 0; ic < 8; ++ic) W1p[ic][3] = np[ic];        // (c3, c4)
        } else {
            hp1_edge<K, 0>(xlt, w1d, b1d, np);
#pragma unroll
            for (int ic = 0; ic < 8; ++ic) W1p[ic][0] = np[ic] << 16;  // (0, c0)
            hp1_edge<K, 1>(xlt, w1d, b1d, np);
#pragma unroll
            for (int ic = 0; ic < 8; ++ic) W1p[ic][1] = np[ic];        // (c1, c2)
        }
    }

    h2 Pp01 = (h2)(_Float16)0.f, Pp23 = Pp01, Q01 = Pp01, Q23 = Pp01;
    const int SMAX = 23 + P;
    for (int s = 0; s <= SMAX; ++s) {
        // conv2: Y[oc] = (y2[2s], y2[2s+1])
        h2 Y[4];
#pragma unroll
        for (int oc = 0; oc < 4; ++oc) Y[oc] = uh(b2d[oc]);
#pragma unroll
        for (int ic = 0; ic < 8; ++ic) {
            u32 PW[K];
#pragma unroll
            for (int k = 0; k < K; ++k)
                PW[k] = (k & 1) ? __builtin_amdgcn_alignbit(W1p[ic][k / 2 + 1], W1p[ic][k / 2], 16)
                                : W1p[ic][k / 2];
#pragma unroll
            for (int oc = 0; oc < 4; ++oc)
#pragma unroll
                for (int k = 0; k < K; ++k)
                    Y[oc] = pkfma(uh(w2d[(oc * 8 + ic) * K + k]), uh(PW[k]), Y[oc]);
        }
        // hp2 (pool+relu, duplicated) -> shift W2d, append
#pragma unroll
        for (int oc = 0; oc < 4; ++oc) {
            h2 Yr = pkmax0(Y[oc]);
            _Float16 hv = (_Float16)0.5f * (Yr.x + Yr.y);
            u32 d = hu((h2){hv, hv});
            d = (s <= 24) ? d : 0u;
#pragma unroll
            for (int k = 0; k < K - 1; ++k) W2d[oc][k] = W2d[oc][k + 1];
            W2d[oc][K - 1] = d;
        }
        // conv3 at p = s-P, packed over oc pairs
        int p = s - P;
        if (p >= 0) {
            h2 Y01 = uh(b3p[0]), Y23 = uh(b3p[1]);
#pragma unroll
            for (int ic = 0; ic < 4; ++ic)
#pragma unroll
                for (int k = 0; k < K; ++k) {
                    h2 wv = uh(W2d[ic][k]);
                    Y01 = pkfma(uh(w3p[ic * K + k]), wv, Y01);
                    Y23 = pkfma(uh(w3p[4 * K + ic * K + k]), wv, Y23);
                }
            Y01 = pkmax0(Y01); Y23 = pkmax0(Y23);
            if ((p & 1) == 0) { Pp01 = Y01; Pp23 = Y23; }
            else {
                h2 hf = (h2)(_Float16)0.5f;
                h2 O01 = (Pp01 + Y01) * hf;
                h2 O23 = (Pp23 + Y23) * hf;
                int t = p >> 1;
                if ((t & 1) == 0) { Q01 = O01; Q23 = O23; }
                else {
                    int w = t >> 1;
                    orow[0 * 6 + w] = hu((h2){Q01.x, O01.x});
                    orow[1 * 6 + w] = hu((h2){Q01.y, O01.y});
                    orow[2 * 6 + w] = hu((h2){Q23.x, O23.x});
                    orow[3 * 6 + w] = hu((h2){Q23.y, O23.y});
                }
            }
        }
        // advance W1p by one pair (= 2 cols)
        if (s < SMAX) {
            u32 np[8];
            hp1_run<K>(xlt, 2 * s + P + 2, w1d, b1d, np);
#pragma unroll
            for (int ic = 0; ic < 8; ++ic) {
#pragma unroll
                for (int j = 0; j < NW1 - 1; ++j) W1p[ic][j] = W1p[ic][j + 1];
                W1p[ic][NW1 - 1] = np[ic];
            }
        }
    }
}

// feats2 blocked layout: element (b, k = c*112 + f) at
//   feats2[(c*14 + (f>>3)) * ROWE + b*8 + (f&7)]
__global__ __launch_bounds__(256, 2) void feats_kernel(
    const u32* __restrict__ xP, const u32* __restrict__ wpk,
    f16* __restrict__ feats2) {
    __shared__ u32 xl[XPW * 256];       // 53,248 B
    __shared__ u32 obufw[256 * OSTR];   // 25,600 B
    const int c = blockIdx.x;
    const int tid = threadIdx.x;
    const int lane = tid & 63, wid = tid >> 6;
    const int b = blockIdx.y * 256 + tid;

    // stage packed x pairs: row w -> xl[w*256 + tid]
    const u32* src = xP + (size_t)c * XPW * BSZ + blockIdx.y * 256;
    for (int w = wid; w < XPW; w += 4)
        gload_lds16(src + (size_t)w * BSZ + lane * 4, (char*)xl + w * 1024 + lane * 16);
    __syncthreads();

    const u32* xlt = xl + tid;
    const u32* wb = wpk + c * CWS;
    u32* orow = obufw + tid * OSTR;
    u32* dst = (u32*)feats2 + (size_t)c * 14 * (ROWE / 2) + (size_t)b * 4;

    // high branch (K=7) -> chunks 0..5
    run_branch_pk<7>(xlt, wb, orow);
    {
        u32 v[24];
#pragma unroll
        for (int j = 0; j < 24; ++j) v[j] = orow[j];
#pragma unroll
        for (int ch = 0; ch < 6; ++ch)
            *(u32x4*)(dst + (size_t)ch * (ROWE / 2)) =
                (u32x4){v[ch * 4], v[ch * 4 + 1], v[ch * 4 + 2], v[ch * 4 + 3]};
    }
    // low branch (K=3) -> chunks 6..11
    run_branch_pk<3>(xlt, wb + 350, orow);
    {
        u32 v[24];
#pragma unroll
        for (int j = 0; j < 24; ++j) v[j] = orow[j];
#pragma unroll
        for (int ch = 0; ch < 6; ++ch)
            *(u32x4*)(dst + (size_t)(6 + ch) * (ROWE / 2)) =
                (u32x4){v[ch * 4], v[ch * 4 + 1], v[ch * 4 + 2], v[ch * 4 + 3]};
    }
    // residual pooling -> chunks 12..13
    u32 orr[6];
#pragma unroll
    for (int t2 = 0; t2 < 6; ++t2) {
        h2 S0 = uh(xlt[(8 * t2 + 0) * 256]) + uh(xlt[(8 * t2 + 1) * 256]) +
                uh(xlt[(8 * t2 + 2) * 256]) + uh(xlt[(8 * t2 + 3) * 256]);
        h2 S1 = uh(xlt[(8 * t2 + 4) * 256]) + uh(xlt[(8 * t2 + 5) * 256]) +
                uh(xlt[(8 * t2 + 6) * 256]) + uh(xlt[(8 * t2 + 7) * 256]);
        _Float16 o0 = (_Float16)0.125f * (S0.x + S0.y);
        _Float16 o1 = (_Float16)0.125f * (S1.x + S1.y);
        orr[t2] = hu((h2){o0, o1});
    }
    *(u32x4*)(dst + (size_t)12 * (ROWE / 2)) = (u32x4){orr[0], orr[1], orr[2], orr[3]};
    *(u32x4*)(dst + (size_t)13 * (ROWE / 2)) = (u32x4){orr[4], orr[5], 0u, 0u};
}

// zero the pad chunk-rows (k = 7392..7423 -> rows 924..927)
__global__ void zero_pad2(f16* __restrict__ feats2) {
    int idx = blockIdx.x * 256 + threadIdx.x;
    u32* dst = (u32*)(feats2 + (size_t)(CCH * 14) * ROWE);
    if (idx < (4 * ROWE * 2) / 16)
        *(u32x4*)(dst + idx * 4) = (u32x4){0u, 0u, 0u, 0u};
}

// convert fw1 (1936 x 7128 f32) -> padded f16 (2048 x 7424) with per-c pad
__global__ void cvt_fw1(const float* __restrict__ fw1, f16* __restrict__ dst) {
    int n = blockIdx.y;
    int kp = blockIdx.x * 256 + threadIdx.x;
    if (kp >= KP2) return;
    int c2 = kp / FPC, f = kp - c2 * FPC;
    float v = 0.f;
    if (n < NOUT && kp < KF2 && f < 108)
        v = fw1[(size_t)n * KFEAT + c2 * 108 + f];
    dst[(size_t)n * KP2 + kp] = (f16)v;
}

// ---------------------------------------------------------------- FC1 GEMM (split-K=2)
__global__ __launch_bounds__(256) void fc1_gemm(
    const f16* __restrict__ A, const f16* __restrict__ Bw, float* __restrict__ C) {
    __shared__ f16 lds_a[128 * 32];
    __shared__ f16 lds_b[128 * 32];
    const int tid = threadIdx.x;
    const int bm = blockIdx.x, bn = blockIdx.y, kz = blockIdx.z;
    const int wid = tid >> 6, lane = tid & 63;
    const int wm = wid >> 1, wn = wid & 1;

    f32x4 acc[4][4];
#pragma unroll
    for (int i = 0; i < 4; ++i)
#pragma unroll
        for (int j = 0; j < 4; ++j) acc[i][j] = (f32x4){0.f, 0.f, 0.f, 0.f};

    const f16* Bbase = Bw + (size_t)bn * 128 * KP2;
    const int l15 = lane & 15, lhi = lane >> 4;

    const int flat0 = tid, flat1 = 256 + tid;
    const int row0 = flat0 >> 2, kc0 = flat0 & 3;
    const int row1 = flat1 >> 2, kc1 = flat1 & 3;

    const int kbeg = kz * (KP2 / 2), kend = kbeg + KP2 / 2;
    for (int k0 = kbeg; k0 < kend; k0 += 32) {
        __syncthreads();
        gload_lds16(A + (size_t)((k0 >> 3) + kc0) * ROWE + (size_t)(bm * 128 + row0) * 8,
                    (char*)lds_a + flat0 * 16);
        gload_lds16(A + (size_t)((k0 >> 3) + kc1) * ROWE + (size_t)(bm * 128 + row1) * 8,
                    (char*)lds_a + flat1 * 16);
        gload_lds16(Bbase + (size_t)row0 * KP2 + k0 + kc0 * 8, (char*)lds_b + flat0 * 16);
        gload_lds16(Bbase + (size_t)row1 * KP2 + k0 + kc1 * 8, (char*)lds_b + flat1 * 16);
        __syncthreads();

        f16x8 af[4], bf[4];
#pragma unroll
        for (int i = 0; i < 4; ++i) {
            int m = wm * 64 + i * 16 + l15;
            af[i] = *(const f16x8*)(lds_a + m * 32 + lhi * 8);
            int n = wn * 64 + i * 16 + l15;
            bf[i] = *(const f16x8*)(lds_b + n * 32 + lhi * 8);
        }
#pragma unroll
        for (int i = 0; i < 4; ++i)
#pragma unroll
            for (int j = 0; j < 4; ++j)
                acc[i][j] = __builtin_amdgcn_mfma_f32_16x16x32_f16(af[i], bf[j], acc[i][j], 0, 0, 0);
    }

    // epilogue: f32 atomic accumulate (C/D layout col = lane&15, row = (lane>>4)*4+r)
#pragma unroll
    for (int i = 0; i < 4; ++i)
#pragma unroll
        for (int j = 0; j < 4; ++j) {
            int n = bn * 128 + wn * 64 + j * 16 + l15;
#pragma unroll
            for (int r = 0; r < 4; ++r) {
                int m = bm * 128 + wm * 64 + i * 16 + lhi * 4 + r;
                atomicAdd(&C[(size_t)m * NPAD + n], acc[i][j][r]);
            }
        }
}

// bias + relu + f16
__global__ __launch_bounds__(256) void fc1_fin(const float* __restrict__ C,
                                               const float* __restrict__ fb1,
                                               f16* __restrict__ H) {
    size_t i4 = ((size_t)blockIdx.x * 256 + threadIdx.x) * 4;
    int n = (int)(i4 & (NPAD - 1));
    f32x4 v = *(const f32x4*)(C + i4);
    f16 r[4];
#pragma unroll
    for (int j = 0; j < 4; ++j) {
        int nn = n + j;
        float bias = (nn < NOUT) ? fb1[nn] : 0.f;
        r[j] = (f16)fmaxf(v[j] + bias, 0.f);
    }
    *(u32x2*)(H + i4) = (u32x2){hu((h2){r[0], r[1]}), hu((h2){r[2], r[3]})};
}

// ---------------------------------------------------------------- FC2
__global__ __launch_bounds__(64) void fc2_kernel(const f16* __restrict__ H,
                                                 const float* __restrict__ fw2,
                                                 const float* __restrict__ fb2,
                                                 float* __restrict__ out) {
    const int b = blockIdx.x;
    const int t = threadIdx.x;
    const f16* hb = H + (size_t)b * NPAD;
    float acc[14];
#pragma unroll
    for (int o = 0; o < 14; ++o) acc[o] = 0.f;
    for (int k = t; k < NOUT; k += 64) {
        float hv = (float)hb[k];
#pragma unroll
        for (int o = 0; o < 14; ++o) acc[o] += hv * fw2[o * NOUT + k];
    }
#pragma unroll
    for (int o = 0; o < 14; ++o) {
        float v = acc[o];
#pragma unroll
        for (int off = 32; off > 0; off >>= 1) v += __shfl_down(v, off, 64);
        if (t == 0) out[b * 14 + o] = v + fb2[o];
    }
}

// ---------------------------------------------------------------- launcher
extern "C" void kernel_launch(void* const* d_in, const int* in_sizes, int n_in,
                              void* d_out, int out_size, void* d_ws, size_t ws_size,
                              hipStream_t stream) {
    const float* x   = (const float*)d_in[0];
    const float* hw1 = (const float*)d_in[1];
    const float* hb1 = (const float*)d_in[2];
    const float* hw2 = (const float*)d_in[3];
    const float* hb2 = (const float*)d_in[4];
    const float* hw3 = (const float*)d_in[5];
    const float* hb3 = (const float*)d_in[6];
    const float* lw1 = (const float*)d_in[7];
    const float* lb1 = (const float*)d_in[8];
    const float* lw2 = (const float*)d_in[9];
    const float* lb2 = (const float*)d_in[10];
    const float* lw3 = (const float*)d_in[11];
    const float* lb3 = (const float*)d_in[12];
    const float* fw1 = (const float*)d_in[13];
    const float* fb1 = (const float*)d_in[14];
    const float* fw2 = (const float*)d_in[15];
    const float* fb2 = (const float*)d_in[16];

    // workspace (byte offsets; aliases exploit disjoint lifetimes):
    // [0, 60.8M)          feats2
    // [60.8M, 114.9M)     xT (transpose/pack only) -> later C f32 (33.5M) + h f16 (16.8M)
    // [114.9M, 171.1M)    xP (feats only)          -> later fw1H (30.4M)
    // [171.1M, 171.3M)    wpk
    char* wsb = (char*)d_ws;
    f16*  feats2 = (f16*)wsb;
    char* reg2   = wsb + (size_t)NCH2 * ROWE * 2;           // 60,817,408
    f16*  xT     = (f16*)reg2;
    float* C     = (float*)reg2;
    f16*  h      = (f16*)(reg2 + (size_t)BSZ * NPAD * 4);   // after C
    char* reg3   = reg2 + (size_t)LC * BSZ * 2;             // + 54,067,200
    u32*  xP     = (u32*)reg3;
    f16*  fw1H   = (f16*)reg3;
    u32*  wpk    = (u32*)(reg3 + (size_t)CCH * XPW * BSZ * 4);  // + 56,229,888

    transpose_x<<<dim3((LC + 31) / 32, BSZ / 32), 256, 0, stream>>>(x, xT);
    pack_x<<<dim3(CCH, XPW, BSZ / 256), 256, 0, stream>>>(xT, xP);
    prep_w<<<dim3(CCH), 64, 0, stream>>>(hw1, hb1, hw2, hb2, hw3, hb3,
                                         lw1, lb1, lw2, lb2, lw3, lb3, wpk);
    feats_kernel<<<dim3(CCH, BSZ / 256), 256, 0, stream>>>(xP, wpk, feats2);
    zero_pad2<<<dim3(64), 256, 0, stream>>>(feats2);
    cvt_fw1<<<dim3((KP2 + 255) / 256, NPAD), 256, 0, stream>>>(fw1, fw1H);  // xP dead now
    hipMemsetAsync(C, 0, (size_t)BSZ * NPAD * 4, stream);                   // xT dead now
    fc1_gemm<<<dim3(BSZ / 128, NPAD / 128, 2), 256, 0, stream>>>(feats2, fw1H, C);
    fc1_fin<<<dim3(BSZ * NPAD / 4 / 256), 256, 0, stream>>>(C, fb1, h);
    fc2_kernel<<<dim3(BSZ), 64, 0, stream>>>(h, fw2, fb2, (float*)d_out);
}

// Round 8
// 757.107 us; speedup vs baseline: 1.6390x; 1.0344x over previous
//
#include <hip/hip_runtime.h>

typedef _Float16 f16;
typedef _Float16 h2 __attribute__((ext_vector_type(2)));
typedef _Float16 f16x8 __attribute__((ext_vector_type(8)));
typedef float    f32x4 __attribute__((ext_vector_type(4)));
typedef unsigned int u32;
typedef u32 u32x2 __attribute__((ext_vector_type(2)));
typedef u32 u32x4 __attribute__((ext_vector_type(4)));

#define CCH 66
#define LLEN 100
#define BSZ 4096
#define NPAD 2048
#define NOUT 1936
#define KFEAT 7128
#define FPC 112                 // padded features per channel (108 real + 4 zero)
#define KF2 (CCH * FPC)         // 7392
#define KP2 7424                // KF2 padded to x32
#define NCH2 (KP2 / 8)          // 928 chunk-rows in feats2
#define ROWE (BSZ * 8)          // f16 elements per chunk-row (32768)
#define LC (LLEN * CCH)
#define OSTR 25                 // obuf row stride in u32 (odd -> conflict-free, 0 measured R6/R7)
#define XPW 52                  // u32 pair-rows per channel (50 data + 2 zero halo)
#define CWS 512                 // packed-weight stride per channel (u32)

// ---------------------------------------------------------------- async G->LDS
typedef __attribute__((address_space(1))) const u32 gu32;
typedef __attribute__((address_space(3))) u32 lu32;

__device__ __forceinline__ void gload_lds16(const void* g, void* l) {
    __builtin_amdgcn_global_load_lds((gu32*)g, (lu32*)l, 16, 0, 0);
}

// ---------------------------------------------------------------- h2 helpers
__device__ __forceinline__ h2  uh(u32 v) { return __builtin_bit_cast(h2, v); }
__device__ __forceinline__ u32 hu(h2 v)  { return __builtin_bit_cast(u32, v); }
__device__ __forceinline__ h2  pkfma(h2 a, h2 b, h2 c) { return __builtin_elementwise_fma(a, b, c); }
__device__ __forceinline__ h2  pkmax0(h2 a) { h2 z = (h2)(_Float16)0.f; return __builtin_elementwise_max(a, z); }

// ---------------------------------------------------------------- fused transpose+pack
// x [B][L*C] f32 -> xP[c][w][b] u32 = (x[2w], x[2w+1]) f16 pair (w = 0..49)
__global__ __launch_bounds__(256) void xpose_pack(const float* __restrict__ x,
                                                  u32* __restrict__ xP) {
    __shared__ float tile[64][133];     // pad 132->133: write cols conflict-free
    const int w = blockIdx.x;           // l0 = 2w
    const int b0 = blockIdx.y * 64;
    const int tid = threadIdx.x;
    const float* src = x + (size_t)b0 * LC + (size_t)(2 * w) * CCH;
#pragma unroll
    for (int i = 0; i < 33; ++i) {      // 64 rows x 132 cols = 33 x 256
        int f = i * 256 + tid;
        int bi = f / 132, j = f - bi * 132;
        tile[bi][j] = src[(size_t)bi * LC + j];
    }
    __syncthreads();
    const int lane = tid & 63, cg = tid >> 6;
    for (int c = cg; c < CCH; c += 4) {
        u32 v = hu((h2){(_Float16)tile[lane][c], (_Float16)tile[lane][66 + c]});
        xP[((size_t)c * XPW + w) * BSZ + b0 + lane] = v;
    }
}

// zero halo rows w=50,51 of every channel (8192 u32 per c, contiguous)
__global__ __launch_bounds__(256) void zero_halo_xp(u32* __restrict__ xP) {
    const int c = blockIdx.x;
    const int i = blockIdx.y * 256 + threadIdx.x;   // 2048 x u32x4 = 8192 u32
    *(u32x4*)(xP + ((size_t)c * XPW + 50) * BSZ + (size_t)i * 4) = (u32x4){0u, 0u, 0u, 0u};
}

// ---------------------------------------------------------------- packed weights
// per-c layout (u32): high @0: w1d[56] b1d[8] w2d[224] b2d[4] w3p[56] b3p[2]
//                      low @350: w1d[24] b1d[8] w2d[96]  b2d[4] w3p[24] b3p[2]
__device__ __forceinline__ u32 dupf(float v) {
    _Float16 h = (_Float16)v; return hu((h2){h, h});
}
__device__ __forceinline__ u32 pk2f(float a, float b) {
    return hu((h2){(_Float16)a, (_Float16)b});
}

__global__ __launch_bounds__(64) void prep_w(
    const float* __restrict__ hw1, const float* __restrict__ hb1,
    const float* __restrict__ hw2, const float* __restrict__ hb2,
    const float* __restrict__ hw3, const float* __restrict__ hb3,
    const float* __restrict__ lw1, const float* __restrict__ lb1,
    const float* __restrict__ lw2, const float* __restrict__ lb2,
    const float* __restrict__ lw3, const float* __restrict__ lb3,
    u32* __restrict__ wpk) {
    const int c = blockIdx.x, t = threadIdx.x;
    u32* wb = wpk + c * CWS;
    for (int i = t; i < 56; i += 64) wb[i] = dupf(hw1[c * 56 + i]);
    if (t < 8)  wb[56 + t] = dupf(hb1[c * 8 + t]);
    for (int i = t; i < 224; i += 64) wb[64 + i] = dupf(hw2[c * 224 + i]);
    if (t < 4)  wb[288 + t] = dupf(hb2[c * 4 + t]);
    for (int i = t; i < 56; i += 64) {
        int pr = i / 28, j = i - pr * 28;
        wb[292 + i] = pk2f(hw3[c * 112 + 2 * pr * 28 + j], hw3[c * 112 + (2 * pr + 1) * 28 + j]);
    }
    if (t < 2)  wb[348 + t] = pk2f(hb3[c * 4 + 2 * t], hb3[c * 4 + 2 * t + 1]);
    for (int i = t; i < 24; i += 64) wb[350 + i] = dupf(lw1[c * 24 + i]);
    if (t < 8)  wb[374 + t] = dupf(lb1[c * 8 + t]);
    for (int i = t; i < 96; i += 64) wb[382 + i] = dupf(lw2[c * 96 + i]);
    if (t < 4)  wb[478 + t] = dupf(lb2[c * 4 + t]);
    for (int i = t; i < 24; i += 64) {
        int pr = i / 12, j = i - pr * 12;
        wb[482 + i] = pk2f(lw3[c * 48 + 2 * pr * 12 + j], lw3[c * 48 + (2 * pr + 1) * 12 + j]);
    }
    if (t < 2)  wb[506 + t] = pk2f(lb3[c * 4 + 2 * t], lb3[c * 4 + 2 * t + 1]);
}

// ---------------------------------------------------------------- feature pipeline (pk-f16)
// hp1 core: PX[j] = packed x pair starting at u0+j; emits np[ic] = (colA,colB)
template<int K>
__device__ __forceinline__ void hp1_core(const u32* PX, const u32* __restrict__ w1d,
                                         const u32* __restrict__ b1d, u32 msk, u32 np[8]) {
#pragma unroll
    for (int ic = 0; ic < 8; ++ic) {
        h2 bb = uh(b1d[ic]);
        h2 AL = bb, AH = bb;
#pragma unroll
        for (int k = 0; k < K; ++k) {
            h2 w = uh(w1d[ic * K + k]);
            AL = pkfma(w, uh(PX[k]), AL);
            AH = pkfma(w, uh(PX[k + 2]), AH);
        }
        AL = pkmax0(AL); AH = pkmax0(AH);
        _Float16 cA = (_Float16)0.5f * (AL.x + AL.y);
        _Float16 cB = (_Float16)0.5f * (AH.x + AH.y);
        np[ic] = hu((h2){cA, cB}) & msk;
    }
}

// hp1 from a register window A[NA] = packed rows [w0 .. w0+NA-1], w0 = idx-(P+1)/2
template<int K, int NA>
__device__ __forceinline__ void hp1_win(const u32 A[NA], int idx,
                                        const u32* w1d, const u32* b1d, u32 np[8]) {
    u32 PX[K + 2];
#pragma unroll
    for (int j = 0; j < K + 2; ++j)
        PX[j] = (j & 1) ? A[(j + 1) / 2]
                        : __builtin_amdgcn_alignbit(A[j / 2 + 1], A[j / 2], 16);
    u32 m = ((idx < 50) ? 0xFFFFu : 0u) | ((idx + 1 < 50) ? 0xFFFF0000u : 0u);
    hp1_core<K>(PX, w1d, b1d, m, np);
}

// compile-time-idx hp1 for the prologue (handles u<0 as zeros; all folds)
template<int K, int IDX>
__device__ __forceinline__ void hp1_edge(const u32* __restrict__ xg,
                                         const u32* w1d, const u32* b1d, u32 np[8]) {
    constexpr int P = K / 2;
    u32 PX[K + 2];
#pragma unroll
    for (int j = 0; j < K + 2; ++j) {
        int u = 2 * IDX - P + j;
        u32 v;
        if (u < -1)      v = 0u;
        else if (u == -1) v = xg[0] << 16;   // (x[-1]=0, x[0])
        else if (u & 1)  v = __builtin_amdgcn_alignbit(xg[(size_t)((u + 1) / 2) * BSZ],
                                                       xg[(size_t)((u - 1) / 2) * BSZ], 16);
        else             v = xg[(size_t)(u / 2) * BSZ];
        PX[j] = v;
    }
    hp1_core<K>(PX, w1d, b1d, 0xFFFFFFFFu, np);
}

// Full branch, packed-f16, global x reads via sliding register window.
// Rolled s-loop (R4/R5: do NOT unroll).
template<int K>
__device__ __forceinline__ void run_branch_pk(const u32* __restrict__ xg,
                                              const u32* __restrict__ wb,
                                              u32* __restrict__ orow) {
    constexpr int P = K / 2;
    constexpr int NW1 = (K + 1) / 2;
    constexpr int NA = (K == 7) ? 6 : 4;       // packed-row window size
    constexpr int WB = (K == 7) ? 3 : 2;       // first window row (= idx0-(P+1)/2)
    const u32* w1d = wb;
    const u32* b1d = wb + 8 * K;
    const u32* w2d = b1d + 8;
    const u32* b2d = w2d + 32 * K;
    const u32* w3p = b2d + 4;
    const u32* b3p = w3p + 8 * K;

    u32 W1p[8][NW1];
    u32 W2d[4][K];
#pragma unroll
    for (int ic = 0; ic < 8; ++ic)
#pragma unroll
        for (int j = 0; j < NW1; ++j) W1p[ic][j] = 0u;
#pragma unroll
    for (int oc = 0; oc < 4; ++oc)
#pragma unroll
        for (int k = 0; k < K; ++k) W2d[oc][k] = 0u;

    // prologue: fill W1p so cols j hold hp1[-P+j] (zeros for negative)
    {
        u32 np[8];
        if (K == 7) {
            hp1_edge<K, 0>(xg, w1d, b1d, np);
#pragma unroll
            for (int ic = 0; ic < 8; ++ic) W1p[ic][1] = np[ic] << 16;  // (0, c0)
            hp1_edge<K, 1>(xg, w1d, b1d, np);
#pragma unroll
            for (int ic = 0; ic < 8; ++ic) W1p[ic][2] = np[ic];        // (c1, c2)
            hp1_edge<K, 3>(xg, w1d, b1d, np);
#pragma unroll
            for (int ic = 0; ic < 8; ++ic) W1p[ic][3] = np[ic];        // (c3, c4)
        } else {
            hp1_edge<K, 0>(xg, w1d, b1d, np);
#pragma unroll
            for (int ic = 0; ic < 8; ++ic) W1p[ic][0] = np[ic] << 16;  // (0, c0)
            hp1_edge<K, 1>(xg, w1d, b1d, np);
#pragma unroll
            for (int ic = 0; ic < 8; ++ic) W1p[ic][1] = np[ic];        // (c1, c2)
        }
    }

    // init sliding window: rows WB .. WB+NA-1
    u32 XA[NA];
#pragma unroll
    for (int j = 0; j < NA; ++j) XA[j] = xg[(size_t)(WB + j) * BSZ];

    h2 Pp01 = (h2)(_Float16)0.f, Pp23 = Pp01, Q01 = Pp01, Q23 = Pp01;
    const int SMAX = 23 + P;
    for (int s = 0; s <= SMAX; ++s) {
        // conv2: Y[oc] = (y2[2s], y2[2s+1])
        h2 Y[4];
#pragma unroll
        for (int oc = 0; oc < 4; ++oc) Y[oc] = uh(b2d[oc]);
#pragma unroll
        for (int ic = 0; ic < 8; ++ic) {
            u32 PW[K];
#pragma unroll
            for (int k = 0; k < K; ++k)
                PW[k] = (k & 1) ? __builtin_amdgcn_alignbit(W1p[ic][k / 2 + 1], W1p[ic][k / 2], 16)
                                : W1p[ic][k / 2];
#pragma unroll
            for (int oc = 0; oc < 4; ++oc)
#pragma unroll
                for (int k = 0; k < K; ++k)
                    Y[oc] = pkfma(uh(w2d[(oc * 8 + ic) * K + k]), uh(PW[k]), Y[oc]);
        }
        // hp2 (pool+relu, duplicated) -> shift W2d, append
#pragma unroll
        for (int oc = 0; oc < 4; ++oc) {
            h2 Yr = pkmax0(Y[oc]);
            _Float16 hv = (_Float16)0.5f * (Yr.x + Yr.y);
            u32 d = hu((h2){hv, hv});
            d = (s <= 24) ? d : 0u;
#pragma unroll
            for (int k = 0; k < K - 1; ++k) W2d[oc][k] = W2d[oc][k + 1];
            W2d[oc][K - 1] = d;
        }
        // conv3 at p = s-P, packed over oc pairs
        int p = s - P;
        if (p >= 0) {
            h2 Y01 = uh(b3p[0]), Y23 = uh(b3p[1]);
#pragma unroll
            for (int ic = 0; ic < 4; ++ic)
#pragma unroll
                for (int k = 0; k < K; ++k) {
                    h2 wv = uh(W2d[ic][k]);
                    Y01 = pkfma(uh(w3p[ic * K + k]), wv, Y01);
                    Y23 = pkfma(uh(w3p[4 * K + ic * K + k]), wv, Y23);
                }
            Y01 = pkmax0(Y01); Y23 = pkmax0(Y23);
            if ((p & 1) == 0) { Pp01 = Y01; Pp23 = Y23; }
            else {
                h2 hf = (h2)(_Float16)0.5f;
                h2 O01 = (Pp01 + Y01) * hf;
                h2 O23 = (Pp23 + Y23) * hf;
                int t = p >> 1;
                if ((t & 1) == 0) { Q01 = O01; Q23 = O23; }
                else {
                    int w = t >> 1;
                    orow[0 * 6 + w] = hu((h2){Q01.x, O01.x});
                    orow[1 * 6 + w] = hu((h2){Q01.y, O01.y});
                    orow[2 * 6 + w] = hu((h2){Q23.x, O23.x});
                    orow[3 * 6 + w] = hu((h2){Q23.y, O23.y});
                }
            }
        }
        // advance W1p by one pair (= 2 cols) using the register window
        if (s < SMAX) {
            u32 np[8];
            hp1_win<K, NA>(XA, 2 * s + P + 2, w1d, b1d, np);
#pragma unroll
            for (int ic = 0; ic < 8; ++ic) {
#pragma unroll
                for (int j = 0; j < NW1 - 1; ++j) W1p[ic][j] = W1p[ic][j + 1];
                W1p[ic][NW1 - 1] = np[ic];
            }
            // slide window by 2 rows, load 2 new rows (coalesced dword)
#pragma unroll
            for (int j = 0; j < NA - 2; ++j) XA[j] = XA[j + 2];
            XA[NA - 2] = xg[(size_t)(WB + 2 * s + NA) * BSZ];
            XA[NA - 1] = xg[(size_t)(WB + 2 * s + NA + 1) * BSZ];
        }
    }
}

// feats2 blocked layout: element (b, k = c*112 + f) at
//   feats2[(c*14 + (f>>3)) * ROWE + b*8 + (f&7)]
__global__ __launch_bounds__(256, 2) void feats_kernel(
    const u32* __restrict__ xP, const u32* __restrict__ wpk,
    f16* __restrict__ feats2) {
    __shared__ u32 obufw[256 * OSTR];   // 25,600 B only -> up to 6 blocks/CU
    const int c = blockIdx.x;
    const int tid = threadIdx.x;
    const int b = blockIdx.y * 256 + tid;

    const u32* xg = xP + (size_t)c * XPW * BSZ + b;   // packed row w at xg[w*BSZ]
    const u32* wb = wpk + c * CWS;
    u32* orow = obufw + tid * OSTR;
    u32* dst = (u32*)feats2 + (size_t)c * 14 * (ROWE / 2) + (size_t)b * 4;

    // high branch (K=7) -> chunks 0..5
    run_branch_pk<7>(xg, wb, orow);
    {
        u32 v[24];
#pragma unroll
        for (int j = 0; j < 24; ++j) v[j] = orow[j];   // same-thread RAW, no barrier
#pragma unroll
        for (int ch = 0; ch < 6; ++ch)
            *(u32x4*)(dst + (size_t)ch * (ROWE / 2)) =
                (u32x4){v[ch * 4], v[ch * 4 + 1], v[ch * 4 + 2], v[ch * 4 + 3]};
    }
    // low branch (K=3) -> chunks 6..11
    run_branch_pk<3>(xg, wb + 350, orow);
    {
        u32 v[24];
#pragma unroll
        for (int j = 0; j < 24; ++j) v[j] = orow[j];
#pragma unroll
        for (int ch = 0; ch < 6; ++ch)
            *(u32x4*)(dst + (size_t)(6 + ch) * (ROWE / 2)) =
                (u32x4){v[ch * 4], v[ch * 4 + 1], v[ch * 4 + 2], v[ch * 4 + 3]};
    }
    // residual pooling -> chunks 12..13
    u32 orr[6];
#pragma unroll
    for (int t2 = 0; t2 < 6; ++t2) {
        h2 S0 = uh(xg[(size_t)(8 * t2 + 0) * BSZ]) + uh(xg[(size_t)(8 * t2 + 1) * BSZ]) +
                uh(xg[(size_t)(8 * t2 + 2) * BSZ]) + uh(xg[(size_t)(8 * t2 + 3) * BSZ]);
        h2 S1 = uh(xg[(size_t)(8 * t2 + 4) * BSZ]) + uh(xg[(size_t)(8 * t2 + 5) * BSZ]) +
                uh(xg[(size_t)(8 * t2 + 6) * BSZ]) + uh(xg[(size_t)(8 * t2 + 7) * BSZ]);
        _Float16 o0 = (_Float16)0.125f * (S0.x + S0.y);
        _Float16 o1 = (_Float16)0.125f * (S1.x + S1.y);
        orr[t2] = hu((h2){o0, o1});
    }
    *(u32x4*)(dst + (size_t)12 * (ROWE / 2)) = (u32x4){orr[0], orr[1], orr[2], orr[3]};
    *(u32x4*)(dst + (size_t)13 * (ROWE / 2)) = (u32x4){orr[4], orr[5], 0u, 0u};
}

// zero the pad chunk-rows (k = 7392..7423 -> rows 924..927)
__global__ void zero_pad2(f16* __restrict__ feats2) {
    int idx = blockIdx.x * 256 + threadIdx.x;
    u32* dst = (u32*)(feats2 + (size_t)(CCH * 14) * ROWE);
    if (idx < (4 * ROWE * 2) / 16)
        *(u32x4*)(dst + idx * 4) = (u32x4){0u, 0u, 0u, 0u};
}

// convert fw1 (1936 x 7128 f32) -> padded f16 (2048 x 7424) with per-c pad
__global__ void cvt_fw1(const float* __restrict__ fw1, f16* __restrict__ dst) {
    int n = blockIdx.y;
    int kp = blockIdx.x * 256 + threadIdx.x;
    if (kp >= KP2) return;
    int c2 = kp / FPC, f = kp - c2 * FPC;
    float v = 0.f;
    if (n < NOUT && kp < KF2 && f < 108)
        v = fw1[(size_t)n * KFEAT + c2 * 108 + f];
    dst[(size_t)n * KP2 + kp] = (f16)v;
}

// ---------------------------------------------------------------- FC1 GEMM (split-K=2)
__global__ __launch_bounds__(256) void fc1_gemm(
    const f16* __restrict__ A, const f16* __restrict__ Bw, float* __restrict__ C) {
    __shared__ f16 lds_a[128 * 32];
    __shared__ f16 lds_b[128 * 32];
    const int tid = threadIdx.x;
    const int bm = blockIdx.x, bn = blockIdx.y, kz = blockIdx.z;
    const int wid = tid >> 6, lane = tid & 63;
    const int wm = wid >> 1, wn = wid & 1;

    f32x4 acc[4][4];
#pragma unroll
    for (int i = 0; i < 4; ++i)
#pragma unroll
        for (int j = 0; j < 4; ++j) acc[i][j] = (f32x4){0.f, 0.f, 0.f, 0.f};

    const f16* Bbase = Bw + (size_t)bn * 128 * KP2;
    const int l15 = lane & 15, lhi = lane >> 4;

    const int flat0 = tid, flat1 = 256 + tid;
    const int row0 = flat0 >> 2, kc0 = flat0 & 3;
    const int row1 = flat1 >> 2, kc1 = flat1 & 3;

    const int kbeg = kz * (KP2 / 2), kend = kbeg + KP2 / 2;
    for (int k0 = kbeg; k0 < kend; k0 += 32) {
        __syncthreads();
        gload_lds16(A + (size_t)((k0 >> 3) + kc0) * ROWE + (size_t)(bm * 128 + row0) * 8,
                    (char*)lds_a + flat0 * 16);
        gload_lds16(A + (size_t)((k0 >> 3) + kc1) * ROWE + (size_t)(bm * 128 + row1) * 8,
                    (char*)lds_a + flat1 * 16);
        gload_lds16(Bbase + (size_t)row0 * KP2 + k0 + kc0 * 8, (char*)lds_b + flat0 * 16);
        gload_lds16(Bbase + (size_t)row1 * KP2 + k0 + kc1 * 8, (char*)lds_b + flat1 * 16);
        __syncthreads();

        f16x8 af[4], bf[4];
#pragma unroll
        for (int i = 0; i < 4; ++i) {
            int m = wm * 64 + i * 16 + l15;
            af[i] = *(const f16x8*)(lds_a + m * 32 + lhi * 8);
            int n = wn * 64 + i * 16 + l15;
            bf[i] = *(const f16x8*)(lds_b + n * 32 + lhi * 8);
        }
#pragma unroll
        for (int i = 0; i < 4; ++i)
#pragma unroll
            for (int j = 0; j < 4; ++j)
                acc[i][j] = __builtin_amdgcn_mfma_f32_16x16x32_f16(af[i], bf[j], acc[i][j], 0, 0, 0);
    }

    // epilogue: f32 atomic accumulate (C/D layout col = lane&15, row = (lane>>4)*4+r)
#pragma unroll
    for (int i = 0; i < 4; ++i)
#pragma unroll
        for (int j = 0; j < 4; ++j) {
            int n = bn * 128 + wn * 64 + j * 16 + l15;
#pragma unroll
            for (int r = 0; r < 4; ++r) {
                int m = bm * 128 + wm * 64 + i * 16 + lhi * 4 + r;
                atomicAdd(&C[(size_t)m * NPAD + n], acc[i][j][r]);
            }
        }
}

// bias + relu + f16
__global__ __launch_bounds__(256) void fc1_fin(const float* __restrict__ C,
                                               const float* __restrict__ fb1,
                                               f16* __restrict__ H) {
    size_t i4 = ((size_t)blockIdx.x * 256 + threadIdx.x) * 4;
    int n = (int)(i4 & (NPAD - 1));
    f32x4 v = *(const f32x4*)(C + i4);
    f16 r[4];
#pragma unroll
    for (int j = 0; j < 4; ++j) {
        int nn = n + j;
        float bias = (nn < NOUT) ? fb1[nn] : 0.f;
        r[j] = (f16)fmaxf(v[j] + bias, 0.f);
    }
    *(u32x2*)(H + i4) = (u32x2){hu((h2){r[0], r[1]}), hu((h2){r[2], r[3]})};
}

// ---------------------------------------------------------------- FC2
__global__ __launch_bounds__(64) void fc2_kernel(const f16* __restrict__ H,
                                                 const float* __restrict__ fw2,
                                                 const float* __restrict__ fb2,
                                                 float* __restrict__ out) {
    const int b = blockIdx.x;
    const int t = threadIdx.x;
    const f16* hb = H + (size_t)b * NPAD;
    float acc[14];
#pragma unroll
    for (int o = 0; o < 14; ++o) acc[o] = 0.f;
    for (int k = t; k < NOUT; k += 64) {
        float hv = (float)hb[k];
#pragma unroll
        for (int o = 0; o < 14; ++o) acc[o] += hv * fw2[o * NOUT + k];
    }
#pragma unroll
    for (int o = 0; o < 14; ++o) {
        float v = acc[o];
#pragma unroll
        for (int off = 32; off > 0; off >>= 1) v += __shfl_down(v, off, 64);
        if (t == 0) out[b * 14 + o] = v + fb2[o];
    }
}

// ---------------------------------------------------------------- launcher
extern "C" void kernel_launch(void* const* d_in, const int* in_sizes, int n_in,
                              void* d_out, int out_size, void* d_ws, size_t ws_size,
                              hipStream_t stream) {
    const float* x   = (const float*)d_in[0];
    const float* hw1 = (const float*)d_in[1];
    const float* hb1 = (const float*)d_in[2];
    const float* hw2 = (const float*)d_in[3];
    const float* hb2 = (const float*)d_in[4];
    const float* hw3 = (const float*)d_in[5];
    const float* hb3 = (const float*)d_in[6];
    const float* lw1 = (const float*)d_in[7];
    const float* lb1 = (const float*)d_in[8];
    const float* lw2 = (const float*)d_in[9];
    const float* lb2 = (const float*)d_in[10];
    const float* lw3 = (const float*)d_in[11];
    const float* lb3 = (const float*)d_in[12];
    const float* fw1 = (const float*)d_in[13];
    const float* fb1 = (const float*)d_in[14];
    const float* fw2 = (const float*)d_in[15];
    const float* fb2 = (const float*)d_in[16];

    // workspace (byte offsets; aliases exploit disjoint lifetimes):
    // [0, 60.8M)          feats2
    // [60.8M, 114.9M)     C f32 (33.5M) + h f16 (16.8M)
    // [114.9M, ...)       xP (56.23M) -> later fw1H (30.4M); wpk directly after xP
    //                     (hp1 masked overreads past xP (<=115 KB) land inside wpk)
    char* wsb = (char*)d_ws;
    f16*  feats2 = (f16*)wsb;
    char* reg2   = wsb + (size_t)NCH2 * ROWE * 2;           // 60,817,408
    float* C     = (float*)reg2;
    f16*  h      = (f16*)(reg2 + (size_t)BSZ * NPAD * 4);
    char* reg3   = reg2 + 54067200;
    u32*  xP     = (u32*)reg3;
    f16*  fw1H   = (f16*)reg3;                               // aliases xP (after feats)
    u32*  wpk    = (u32*)(reg3 + (size_t)CCH * XPW * BSZ * 4);

    xpose_pack<<<dim3(50, BSZ / 64), 256, 0, stream>>>(x, xP);
    zero_halo_xp<<<dim3(CCH, 8), 256, 0, stream>>>(xP);
    prep_w<<<dim3(CCH), 64, 0, stream>>>(hw1, hb1, hw2, hb2, hw3, hb3,
                                         lw1, lb1, lw2, lb2, lw3, lb3, wpk);
    feats_kernel<<<dim3(CCH, BSZ / 256), 256, 0, stream>>>(xP, wpk, feats2);
    zero_pad2<<<dim3(64), 256, 0, stream>>>(feats2);
    cvt_fw1<<<dim3((KP2 + 255) / 256, NPAD), 256, 0, stream>>>(fw1, fw1H);  // xP dead now
    hipMemsetAsync(C, 0, (size_t)BSZ * NPAD * 4, stream);
    fc1_gemm<<<dim3(BSZ / 128, NPAD / 128, 2), 256, 0, stream>>>(feats2, fw1H, C);
    fc1_fin<<<dim3(BSZ * NPAD / 4 / 256), 256, 0, stream>>>(C, fb1, h);
    fc2_kernel<<<dim3(BSZ), 64, 0, stream>>>(h, fw2, fb2, (float*)d_out);
}

// Round 9
// 692.895 us; speedup vs baseline: 1.7909x; 1.0927x over previous
//
#include <hip/hip_runtime.h>

typedef _Float16 f16;
typedef _Float16 h2 __attribute__((ext_vector_type(2)));
typedef _Float16 f16x8 __attribute__((ext_vector_type(8)));
typedef float    f32x4 __attribute__((ext_vector_type(4)));
typedef unsigned int u32;
typedef u32 u32x2 __attribute__((ext_vector_type(2)));
typedef u32 u32x4 __attribute__((ext_vector_type(4)));

#define CCH 66
#define LLEN 100
#define BSZ 4096
#define NPAD 2048
#define NOUT 1936
#define KFEAT 7128
#define FPC 112                 // padded features per channel (108 real + 4 zero)
#define KF2 (CCH * FPC)         // 7392
#define KP2 7424                // KF2 padded to x32
#define NCH2 (KP2 / 8)          // 928 chunk-rows in feats2
#define ROWE (BSZ * 8)          // f16 elements per chunk-row (32768)
#define LC (LLEN * CCH)
#define OSTR 25                 // obuf row stride in u32 (odd -> conflict-free, 0 measured R6/R7)
#define XPW 52                  // u32 pair-rows per channel (50 data + 2 zero halo)
#define CWS 512                 // packed-weight stride per channel (u32)

// ---------------------------------------------------------------- async G->LDS
typedef __attribute__((address_space(1))) const u32 gu32;
typedef __attribute__((address_space(3))) u32 lu32;

__device__ __forceinline__ void gload_lds16(const void* g, void* l) {
    __builtin_amdgcn_global_load_lds((gu32*)g, (lu32*)l, 16, 0, 0);
}

// ---------------------------------------------------------------- h2 helpers
__device__ __forceinline__ h2  uh(u32 v) { return __builtin_bit_cast(h2, v); }
__device__ __forceinline__ u32 hu(h2 v)  { return __builtin_bit_cast(u32, v); }
__device__ __forceinline__ h2  pkfma(h2 a, h2 b, h2 c) { return __builtin_elementwise_fma(a, b, c); }
__device__ __forceinline__ h2  pkmax0(h2 a) { h2 z = (h2)(_Float16)0.f; return __builtin_elementwise_max(a, z); }

// ---------------------------------------------------------------- fused transpose+pack
// x [B][L*C] f32 -> xP[c][w][b] u32 = (x[2w], x[2w+1]) f16 pair (w = 0..49)
__global__ __launch_bounds__(256) void xpose_pack(const float* __restrict__ x,
                                                  u32* __restrict__ xP) {
    __shared__ float tile[64][133];     // pad 132->133: write cols conflict-free
    const int w = blockIdx.x;           // l0 = 2w
    const int b0 = blockIdx.y * 64;
    const int tid = threadIdx.x;
    const float* src = x + (size_t)b0 * LC + (size_t)(2 * w) * CCH;
#pragma unroll
    for (int i = 0; i < 33; ++i) {      // 64 rows x 132 cols = 33 x 256
        int f = i * 256 + tid;
        int bi = f / 132, j = f - bi * 132;
        tile[bi][j] = src[(size_t)bi * LC + j];
    }
    __syncthreads();
    const int lane = tid & 63, cg = tid >> 6;
    for (int c = cg; c < CCH; c += 4) {
        u32 v = hu((h2){(_Float16)tile[lane][c], (_Float16)tile[lane][66 + c]});
        xP[((size_t)c * XPW + w) * BSZ + b0 + lane] = v;
    }
}

// zero halo rows w=50,51 of every channel (8192 u32 per c, contiguous)
__global__ __launch_bounds__(256) void zero_halo_xp(u32* __restrict__ xP) {
    const int c = blockIdx.x;
    const int i = blockIdx.y * 256 + threadIdx.x;   // 2048 x u32x4 = 8192 u32
    *(u32x4*)(xP + ((size_t)c * XPW + 50) * BSZ + (size_t)i * 4) = (u32x4){0u, 0u, 0u, 0u};
}

// ---------------------------------------------------------------- packed weights
// per-c layout (u32): high @0: w1d[56] b1d[8] w2d[224] b2d[4] w3p[56] b3p[2]
//                      low @350: w1d[24] b1d[8] w2d[96]  b2d[4] w3p[24] b3p[2]
__device__ __forceinline__ u32 dupf(float v) {
    _Float16 h = (_Float16)v; return hu((h2){h, h});
}
__device__ __forceinline__ u32 pk2f(float a, float b) {
    return hu((h2){(_Float16)a, (_Float16)b});
}

__global__ __launch_bounds__(64) void prep_w(
    const float* __restrict__ hw1, const float* __restrict__ hb1,
    const float* __restrict__ hw2, const float* __restrict__ hb2,
    const float* __restrict__ hw3, const float* __restrict__ hb3,
    const float* __restrict__ lw1, const float* __restrict__ lb1,
    const float* __restrict__ lw2, const float* __restrict__ lb2,
    const float* __restrict__ lw3, const float* __restrict__ lb3,
    u32* __restrict__ wpk) {
    const int c = blockIdx.x, t = threadIdx.x;
    u32* wb = wpk + c * CWS;
    for (int i = t; i < 56; i += 64) wb[i] = dupf(hw1[c * 56 + i]);
    if (t < 8)  wb[56 + t] = dupf(hb1[c * 8 + t]);
    for (int i = t; i < 224; i += 64) wb[64 + i] = dupf(hw2[c * 224 + i]);
    if (t < 4)  wb[288 + t] = dupf(hb2[c * 4 + t]);
    for (int i = t; i < 56; i += 64) {
        int pr = i / 28, j = i - pr * 28;
        wb[292 + i] = pk2f(hw3[c * 112 + 2 * pr * 28 + j], hw3[c * 112 + (2 * pr + 1) * 28 + j]);
    }
    if (t < 2)  wb[348 + t] = pk2f(hb3[c * 4 + 2 * t], hb3[c * 4 + 2 * t + 1]);
    for (int i = t; i < 24; i += 64) wb[350 + i] = dupf(lw1[c * 24 + i]);
    if (t < 8)  wb[374 + t] = dupf(lb1[c * 8 + t]);
    for (int i = t; i < 96; i += 64) wb[382 + i] = dupf(lw2[c * 96 + i]);
    if (t < 4)  wb[478 + t] = dupf(lb2[c * 4 + t]);
    for (int i = t; i < 24; i += 64) {
        int pr = i / 12, j = i - pr * 12;
        wb[482 + i] = pk2f(lw3[c * 48 + 2 * pr * 12 + j], lw3[c * 48 + (2 * pr + 1) * 12 + j]);
    }
    if (t < 2)  wb[506 + t] = pk2f(lb3[c * 4 + 2 * t], lb3[c * 4 + 2 * t + 1]);
}

// ---------------------------------------------------------------- feature pipeline (pk-f16)
// hp1 core: PX[j] = packed x pair starting at u0+j; emits np[ic] = (colA,colB)
template<int K>
__device__ __forceinline__ void hp1_core(const u32* PX, const u32* __restrict__ w1d,
                                         const u32* __restrict__ b1d, u32 msk, u32 np[8]) {
#pragma unroll
    for (int ic = 0; ic < 8; ++ic) {
        h2 bb = uh(b1d[ic]);
        h2 AL = bb, AH = bb;
#pragma unroll
        for (int k = 0; k < K; ++k) {
            h2 w = uh(w1d[ic * K + k]);
            AL = pkfma(w, uh(PX[k]), AL);
            AH = pkfma(w, uh(PX[k + 2]), AH);
        }
        AL = pkmax0(AL); AH = pkmax0(AH);
        _Float16 cA = (_Float16)0.5f * (AL.x + AL.y);
        _Float16 cB = (_Float16)0.5f * (AH.x + AH.y);
        np[ic] = hu((h2){cA, cB}) & msk;
    }
}

// hp1 from a register window A[NA] = packed rows [w0 .. w0+NA-1], w0 = idx-(P+1)/2
template<int K, int NA>
__device__ __forceinline__ void hp1_win(const u32 A[NA], int idx,
                                        const u32* w1d, const u32* b1d, u32 np[8]) {
    u32 PX[K + 2];
#pragma unroll
    for (int j = 0; j < K + 2; ++j)
        PX[j] = (j & 1) ? A[(j + 1) / 2]
                        : __builtin_amdgcn_alignbit(A[j / 2 + 1], A[j / 2], 16);
    u32 m = ((idx < 50) ? 0xFFFFu : 0u) | ((idx + 1 < 50) ? 0xFFFF0000u : 0u);
    hp1_core<K>(PX, w1d, b1d, m, np);
}

// compile-time-idx hp1 for the prologue (handles u<0 as zeros; all folds)
template<int K, int IDX>
__device__ __forceinline__ void hp1_edge(const u32* __restrict__ xg,
                                         const u32* w1d, const u32* b1d, u32 np[8]) {
    constexpr int P = K / 2;
    u32 PX[K + 2];
#pragma unroll
    for (int j = 0; j < K + 2; ++j) {
        int u = 2 * IDX - P + j;
        u32 v;
        if (u < -1)      v = 0u;
        else if (u == -1) v = xg[0] << 16;   // (x[-1]=0, x[0])
        else if (u & 1)  v = __builtin_amdgcn_alignbit(xg[(size_t)((u + 1) / 2) * BSZ],
                                                       xg[(size_t)((u - 1) / 2) * BSZ], 16);
        else             v = xg[(size_t)(u / 2) * BSZ];
        PX[j] = v;
    }
    hp1_core<K>(PX, w1d, b1d, 0xFFFFFFFFu, np);
}

// Full branch, packed-f16, global x reads via sliding register window.
// Rolled s-loop (R4/R5: do NOT unroll).
template<int K>
__device__ __forceinline__ void run_branch_pk(const u32* __restrict__ xg,
                                              const u32* __restrict__ wb,
                                              u32* __restrict__ orow) {
    constexpr int P = K / 2;
    constexpr int NW1 = (K + 1) / 2;
    constexpr int NA = (K == 7) ? 6 : 4;       // packed-row window size
    constexpr int WB = (K == 7) ? 3 : 2;       // first window row (= idx0-(P+1)/2)
    const u32* w1d = wb;
    const u32* b1d = wb + 8 * K;
    const u32* w2d = b1d + 8;
    const u32* b2d = w2d + 32 * K;
    const u32* w3p = b2d + 4;
    const u32* b3p = w3p + 8 * K;

    u32 W1p[8][NW1];
    u32 W2d[4][K];
#pragma unroll
    for (int ic = 0; ic < 8; ++ic)
#pragma unroll
        for (int j = 0; j < NW1; ++j) W1p[ic][j] = 0u;
#pragma unroll
    for (int oc = 0; oc < 4; ++oc)
#pragma unroll
        for (int k = 0; k < K; ++k) W2d[oc][k] = 0u;

    // prologue: fill W1p so cols j hold hp1[-P+j] (zeros for negative)
    {
        u32 np[8];
        if (K == 7) {
            hp1_edge<K, 0>(xg, w1d, b1d, np);
#pragma unroll
            for (int ic = 0; ic < 8; ++ic) W1p[ic][1] = np[ic] << 16;  // (0, c0)
            hp1_edge<K, 1>(xg, w1d, b1d, np);
#pragma unroll
            for (int ic = 0; ic < 8; ++ic) W1p[ic][2] = np[ic];        // (c1, c2)
            hp1_edge<K, 3>(xg, w1d, b1d, np);
#pragma unroll
            for (int ic = 0; ic < 8; ++ic) W1p[ic][3] = np[ic];        // (c3, c4)
        } else {
            hp1_edge<K, 0>(xg, w1d, b1d, np);
#pragma unroll
            for (int ic = 0; ic < 8; ++ic) W1p[ic][0] = np[ic] << 16;  // (0, c0)
            hp1_edge<K, 1>(xg, w1d, b1d, np);
#pragma unroll
            for (int ic = 0; ic < 8; ++ic) W1p[ic][1] = np[ic];        // (c1, c2)
        }
    }

    // init sliding window: rows WB .. WB+NA-1
    u32 XA[NA];
#pragma unroll
    for (int j = 0; j < NA; ++j) XA[j] = xg[(size_t)(WB + j) * BSZ];

    h2 Pp01 = (h2)(_Float16)0.f, Pp23 = Pp01, Q01 = Pp01, Q23 = Pp01;
    const int SMAX = 23 + P;
    for (int s = 0; s <= SMAX; ++s) {
        // conv2: Y[oc] = (y2[2s], y2[2s+1])
        h2 Y[4];
#pragma unroll
        for (int oc = 0; oc < 4; ++oc) Y[oc] = uh(b2d[oc]);
#pragma unroll
        for (int ic = 0; ic < 8; ++ic) {
            u32 PW[K];
#pragma unroll
            for (int k = 0; k < K; ++k)
                PW[k] = (k & 1) ? __builtin_amdgcn_alignbit(W1p[ic][k / 2 + 1], W1p[ic][k / 2], 16)
                                : W1p[ic][k / 2];
#pragma unroll
            for (int oc = 0; oc < 4; ++oc)
#pragma unroll
                for (int k = 0; k < K; ++k)
                    Y[oc] = pkfma(uh(w2d[(oc * 8 + ic) * K + k]), uh(PW[k]), Y[oc]);
        }
        // hp2 (pool+relu, duplicated) -> shift W2d, append
#pragma unroll
        for (int oc = 0; oc < 4; ++oc) {
            h2 Yr = pkmax0(Y[oc]);
            _Float16 hv = (_Float16)0.5f * (Yr.x + Yr.y);
            u32 d = hu((h2){hv, hv});
            d = (s <= 24) ? d : 0u;
#pragma unroll
            for (int k = 0; k < K - 1; ++k) W2d[oc][k] = W2d[oc][k + 1];
            W2d[oc][K - 1] = d;
        }
        // conv3 at p = s-P, packed over oc pairs
        int p = s - P;
        if (p >= 0) {
            h2 Y01 = uh(b3p[0]), Y23 = uh(b3p[1]);
#pragma unroll
            for (int ic = 0; ic < 4; ++ic)
#pragma unroll
                for (int k = 0; k < K; ++k) {
                    h2 wv = uh(W2d[ic][k]);
                    Y01 = pkfma(uh(w3p[ic * K + k]), wv, Y01);
                    Y23 = pkfma(uh(w3p[4 * K + ic * K + k]), wv, Y23);
                }
            Y01 = pkmax0(Y01); Y23 = pkmax0(Y23);
            if ((p & 1) == 0) { Pp01 = Y01; Pp23 = Y23; }
            else {
                h2 hf = (h2)(_Float16)0.5f;
                h2 O01 = (Pp01 + Y01) * hf;
                h2 O23 = (Pp23 + Y23) * hf;
                int t = p >> 1;
                if ((t & 1) == 0) { Q01 = O01; Q23 = O23; }
                else {
                    int w = t >> 1;
                    orow[0 * 6 + w] = hu((h2){Q01.x, O01.x});
                    orow[1 * 6 + w] = hu((h2){Q01.y, O01.y});
                    orow[2 * 6 + w] = hu((h2){Q23.x, O23.x});
                    orow[3 * 6 + w] = hu((h2){Q23.y, O23.y});
                }
            }
        }
        // advance W1p by one pair (= 2 cols) using the register window
        if (s < SMAX) {
            u32 np[8];
            hp1_win<K, NA>(XA, 2 * s + P + 2, w1d, b1d, np);
#pragma unroll
            for (int ic = 0; ic < 8; ++ic) {
#pragma unroll
                for (int j = 0; j < NW1 - 1; ++j) W1p[ic][j] = W1p[ic][j + 1];
                W1p[ic][NW1 - 1] = np[ic];
            }
            // slide window by 2 rows, load 2 new rows (coalesced dword)
#pragma unroll
            for (int j = 0; j < NA - 2; ++j) XA[j] = XA[j + 2];
            XA[NA - 2] = xg[(size_t)(WB + 2 * s + NA) * BSZ];
            XA[NA - 1] = xg[(size_t)(WB + 2 * s + NA + 1) * BSZ];
        }
    }
}

// feats2 blocked layout: element (b, k = c*112 + f) at
//   feats2[(c*14 + (f>>3)) * ROWE + b*8 + (f&7)]
// blockIdx.z: 0 = high branch (K=7, chunks 0..5), 1 = low branch + residual (6..13)
__global__ __launch_bounds__(256, 2) void feats_kernel(
    const u32* __restrict__ xP, const u32* __restrict__ wpk,
    f16* __restrict__ feats2) {
    __shared__ u32 obufw[256 * OSTR];   // 25,600 B
    const int c = blockIdx.x;
    const int tid = threadIdx.x;
    const int b = blockIdx.y * 256 + tid;

    const u32* xg = xP + (size_t)c * XPW * BSZ + b;   // packed row w at xg[w*BSZ]
    const u32* wb = wpk + c * CWS;
    u32* orow = obufw + tid * OSTR;
    u32* dst = (u32*)feats2 + (size_t)c * 14 * (ROWE / 2) + (size_t)b * 4;

    if (blockIdx.z == 0) {
        // high branch (K=7) -> chunks 0..5
        run_branch_pk<7>(xg, wb, orow);
        u32 v[24];
#pragma unroll
        for (int j = 0; j < 24; ++j) v[j] = orow[j];   // same-thread RAW, no barrier
#pragma unroll
        for (int ch = 0; ch < 6; ++ch)
            *(u32x4*)(dst + (size_t)ch * (ROWE / 2)) =
                (u32x4){v[ch * 4], v[ch * 4 + 1], v[ch * 4 + 2], v[ch * 4 + 3]};
    } else {
        // low branch (K=3) -> chunks 6..11
        run_branch_pk<3>(xg, wb + 350, orow);
        u32 v[24];
#pragma unroll
        for (int j = 0; j < 24; ++j) v[j] = orow[j];
#pragma unroll
        for (int ch = 0; ch < 6; ++ch)
            *(u32x4*)(dst + (size_t)(6 + ch) * (ROWE / 2)) =
                (u32x4){v[ch * 4], v[ch * 4 + 1], v[ch * 4 + 2], v[ch * 4 + 3]};
        // residual pooling -> chunks 12..13
        u32 orr[6];
#pragma unroll
        for (int t2 = 0; t2 < 6; ++t2) {
            h2 S0 = uh(xg[(size_t)(8 * t2 + 0) * BSZ]) + uh(xg[(size_t)(8 * t2 + 1) * BSZ]) +
                    uh(xg[(size_t)(8 * t2 + 2) * BSZ]) + uh(xg[(size_t)(8 * t2 + 3) * BSZ]);
            h2 S1 = uh(xg[(size_t)(8 * t2 + 4) * BSZ]) + uh(xg[(size_t)(8 * t2 + 5) * BSZ]) +
                    uh(xg[(size_t)(8 * t2 + 6) * BSZ]) + uh(xg[(size_t)(8 * t2 + 7) * BSZ]);
            _Float16 o0 = (_Float16)0.125f * (S0.x + S0.y);
            _Float16 o1 = (_Float16)0.125f * (S1.x + S1.y);
            orr[t2] = hu((h2){o0, o1});
        }
        *(u32x4*)(dst + (size_t)12 * (ROWE / 2)) = (u32x4){orr[0], orr[1], orr[2], orr[3]};
        *(u32x4*)(dst + (size_t)13 * (ROWE / 2)) = (u32x4){orr[4], orr[5], 0u, 0u};
    }
}

// zero the pad chunk-rows (k = 7392..7423 -> rows 924..927)
__global__ void zero_pad2(f16* __restrict__ feats2) {
    int idx = blockIdx.x * 256 + threadIdx.x;
    u32* dst = (u32*)(feats2 + (size_t)(CCH * 14) * ROWE);
    if (idx < (4 * ROWE * 2) / 16)
        *(u32x4*)(dst + idx * 4) = (u32x4){0u, 0u, 0u, 0u};
}

// convert fw1 (1936 x 7128 f32) -> padded f16 (2048 x 7424) with per-c pad
__global__ void cvt_fw1(const float* __restrict__ fw1, f16* __restrict__ dst) {
    int n = blockIdx.y;
    int kp = blockIdx.x * 256 + threadIdx.x;
    if (kp >= KP2) return;
    int c2 = kp / FPC, f = kp - c2 * FPC;
    float v = 0.f;
    if (n < NOUT && kp < KF2 && f < 108)
        v = fw1[(size_t)n * KFEAT + c2 * 108 + f];
    dst[(size_t)n * KP2 + kp] = (f16)v;
}

// ---------------------------------------------------------------- FC1 GEMM
// A in feats2 blocked layout; Bw [n][KP2]; H = relu(A.Bw^T + fb1) f16 [m][NPAD]
// (non-split-K, direct epilogue — R6-proven; split-K=2+atomics cost ~40us net)
__global__ __launch_bounds__(256) void fc1_gemm(
    const f16* __restrict__ A, const f16* __restrict__ Bw,
    const float* __restrict__ fb1, f16* __restrict__ H) {
    __shared__ f16 lds_a[128 * 32];
    __shared__ f16 lds_b[128 * 32];
    const int tid = threadIdx.x;
    const int bm = blockIdx.x;  // 32 tiles of M
    const int bn = blockIdx.y;  // 16 tiles of N
    const int wid = tid >> 6, lane = tid & 63;
    const int wm = wid >> 1, wn = wid & 1;

    f32x4 acc[4][4];
#pragma unroll
    for (int i = 0; i < 4; ++i)
#pragma unroll
        for (int j = 0; j < 4; ++j) acc[i][j] = (f32x4){0.f, 0.f, 0.f, 0.f};

    const f16* Bbase = Bw + (size_t)bn * 128 * KP2;
    const int l15 = lane & 15, lhi = lane >> 4;

    const int flat0 = tid, flat1 = 256 + tid;
    const int row0 = flat0 >> 2, kc0 = flat0 & 3;
    const int row1 = flat1 >> 2, kc1 = flat1 & 3;

    for (int k0 = 0; k0 < KP2; k0 += 32) {
        __syncthreads();
        gload_lds16(A + (size_t)((k0 >> 3) + kc0) * ROWE + (size_t)(bm * 128 + row0) * 8,
                    (char*)lds_a + flat0 * 16);
        gload_lds16(A + (size_t)((k0 >> 3) + kc1) * ROWE + (size_t)(bm * 128 + row1) * 8,
                    (char*)lds_a + flat1 * 16);
        gload_lds16(Bbase + (size_t)row0 * KP2 + k0 + kc0 * 8, (char*)lds_b + flat0 * 16);
        gload_lds16(Bbase + (size_t)row1 * KP2 + k0 + kc1 * 8, (char*)lds_b + flat1 * 16);
        __syncthreads();

        f16x8 af[4], bf[4];
#pragma unroll
        for (int i = 0; i < 4; ++i) {
            int m = wm * 64 + i * 16 + l15;
            af[i] = *(const f16x8*)(lds_a + m * 32 + lhi * 8);
            int n = wn * 64 + i * 16 + l15;
            bf[i] = *(const f16x8*)(lds_b + n * 32 + lhi * 8);
        }
#pragma unroll
        for (int i = 0; i < 4; ++i)
#pragma unroll
            for (int j = 0; j < 4; ++j)
                acc[i][j] = __builtin_amdgcn_mfma_f32_16x16x32_f16(af[i], bf[j], acc[i][j], 0, 0, 0);
    }

    // epilogue: C/D layout col = lane&15, row = (lane>>4)*4 + r
#pragma unroll
    for (int i = 0; i < 4; ++i) {
#pragma unroll
        for (int j = 0; j < 4; ++j) {
            int n = bn * 128 + wn * 64 + j * 16 + l15;
            float bias = (n < NOUT) ? fb1[n] : 0.f;
#pragma unroll
            for (int r = 0; r < 4; ++r) {
                int m = bm * 128 + wm * 64 + i * 16 + lhi * 4 + r;
                float v = acc[i][j][r] + bias;
                H[(size_t)m * NPAD + n] = (f16)fmaxf(v, 0.f);
            }
        }
    }
}

// ---------------------------------------------------------------- FC2
__global__ __launch_bounds__(64) void fc2_kernel(const f16* __restrict__ H,
                                                 const float* __restrict__ fw2,
                                                 const float* __restrict__ fb2,
                                                 float* __restrict__ out) {
    const int b = blockIdx.x;
    const int t = threadIdx.x;
    const f16* hb = H + (size_t)b * NPAD;
    float acc[14];
#pragma unroll
    for (int o = 0; o < 14; ++o) acc[o] = 0.f;
    for (int k = t; k < NOUT; k += 64) {
        float hv = (float)hb[k];
#pragma unroll
        for (int o = 0; o < 14; ++o) acc[o] += hv * fw2[o * NOUT + k];
    }
#pragma unroll
    for (int o = 0; o < 14; ++o) {
        float v = acc[o];
#pragma unroll
        for (int off = 32; off > 0; off >>= 1) v += __shfl_down(v, off, 64);
        if (t == 0) out[b * 14 + o] = v + fb2[o];
    }
}

// ---------------------------------------------------------------- launcher
extern "C" void kernel_launch(void* const* d_in, const int* in_sizes, int n_in,
                              void* d_out, int out_size, void* d_ws, size_t ws_size,
                              hipStream_t stream) {
    const float* x   = (const float*)d_in[0];
    const float* hw1 = (const float*)d_in[1];
    const float* hb1 = (const float*)d_in[2];
    const float* hw2 = (const float*)d_in[3];
    const float* hb2 = (const float*)d_in[4];
    const float* hw3 = (const float*)d_in[5];
    const float* hb3 = (const float*)d_in[6];
    const float* lw1 = (const float*)d_in[7];
    const float* lb1 = (const float*)d_in[8];
    const float* lw2 = (const float*)d_in[9];
    const float* lb2 = (const float*)d_in[10];
    const float* lw3 = (const float*)d_in[11];
    const float* lb3 = (const float*)d_in[12];
    const float* fw1 = (const float*)d_in[13];
    const float* fb1 = (const float*)d_in[14];
    const float* fw2 = (const float*)d_in[15];
    const float* fb2 = (const float*)d_in[16];

    // workspace (byte offsets; aliases exploit disjoint lifetimes):
    // [0, 60.8M)          feats2
    // [60.8M, 77.6M)      h f16 (16.8M)
    // [114.9M, ...)       xP (56.23M) -> later fw1H (30.4M); wpk directly after xP
    //                     (hp1 masked overreads past xP land inside wpk region)
    char* wsb = (char*)d_ws;
    f16*  feats2 = (f16*)wsb;
    char* reg2   = wsb + (size_t)NCH2 * ROWE * 2;           // 60,817,408
    f16*  h      = (f16*)reg2;
    char* reg3   = reg2 + 54067200;
    u32*  xP     = (u32*)reg3;
    f16*  fw1H   = (f16*)reg3;                               // aliases xP (after feats)
    u32*  wpk    = (u32*)(reg3 + (size_t)CCH * XPW * BSZ * 4);

    xpose_pack<<<dim3(50, BSZ / 64), 256, 0, stream>>>(x, xP);
    zero_halo_xp<<<dim3(CCH, 8), 256, 0, stream>>>(xP);
    prep_w<<<dim3(CCH), 64, 0, stream>>>(hw1, hb1, hw2, hb2, hw3, hb3,
                                         lw1, lb1, lw2, lb2, lw3, lb3, wpk);
    feats_kernel<<<dim3(CCH, BSZ / 256, 2), 256, 0, stream>>>(xP, wpk, feats2);
    zero_pad2<<<dim3(64), 256, 0, stream>>>(feats2);
    cvt_fw1<<<dim3((KP2 + 255) / 256, NPAD), 256, 0, stream>>>(fw1, fw1H);  // xP dead now
    fc1_gemm<<<dim3(BSZ / 128, NPAD / 128), 256, 0, stream>>>(feats2, fw1H, fb1, h);
    fc2_kernel<<<dim3(BSZ), 64, 0, stream>>>(h, fw2, fb2, (float*)d_out);
}

// Round 10
// 691.352 us; speedup vs baseline: 1.7949x; 1.0022x over previous
//
#include <hip/hip_runtime.h>

typedef _Float16 f16;
typedef _Float16 h2 __attribute__((ext_vector_type(2)));
typedef _Float16 f16x8 __attribute__((ext_vector_type(8)));
typedef float    f32x4 __attribute__((ext_vector_type(4)));
typedef unsigned int u32;
typedef u32 u32x2 __attribute__((ext_vector_type(2)));
typedef u32 u32x4 __attribute__((ext_vector_type(4)));

#define CCH 66
#define LLEN 100
#define BSZ 4096
#define NPAD 2048
#define NOUT 1936
#define KFEAT 7128
#define FPC 112                 // padded features per channel (108 real + 4 zero)
#define KF2 (CCH * FPC)         // 7392
#define KP2 7424                // KF2 padded to x32
#define NCH2 (KP2 / 8)          // 928 chunk-rows in feats2
#define ROWE (BSZ * 8)          // f16 elements per chunk-row (32768)
#define LC (LLEN * CCH)
#define OSTR 25                 // obuf row stride in u32 (odd -> conflict-free, 0 measured R6-R9)
#define XPW 52                  // u32 pair-rows per channel (50 data + 2 zero halo)
#define CWS 512                 // packed-weight stride per channel (u32)

// ---------------------------------------------------------------- async G->LDS
typedef __attribute__((address_space(1))) const u32 gu32;
typedef __attribute__((address_space(3))) u32 lu32;

__device__ __forceinline__ void gload_lds16(const void* g, void* l) {
    __builtin_amdgcn_global_load_lds((gu32*)g, (lu32*)l, 16, 0, 0);
}

// ---------------------------------------------------------------- h2 helpers
__device__ __forceinline__ h2  uh(u32 v) { return __builtin_bit_cast(h2, v); }
__device__ __forceinline__ u32 hu(h2 v)  { return __builtin_bit_cast(u32, v); }
__device__ __forceinline__ h2  pkfma(h2 a, h2 b, h2 c) { return __builtin_elementwise_fma(a, b, c); }
__device__ __forceinline__ h2  pkmax0(h2 a) { h2 z = (h2)(_Float16)0.f; return __builtin_elementwise_max(a, z); }

// ---------------------------------------------------------------- fused transpose+pack
// x [B][L*C] f32 -> xP[c][w][b] u32 = (x[2w], x[2w+1]) f16 pair (w = 0..49)
__global__ __launch_bounds__(256) void xpose_pack(const float* __restrict__ x,
                                                  u32* __restrict__ xP) {
    __shared__ float tile[64][133];     // pad 132->133: write cols conflict-free
    const int w = blockIdx.x;           // l0 = 2w
    const int b0 = blockIdx.y * 64;
    const int tid = threadIdx.x;
    const float* src = x + (size_t)b0 * LC + (size_t)(2 * w) * CCH;
#pragma unroll
    for (int i = 0; i < 33; ++i) {      // 64 rows x 132 cols = 33 x 256
        int f = i * 256 + tid;
        int bi = f / 132, j = f - bi * 132;
        tile[bi][j] = src[(size_t)bi * LC + j];
    }
    __syncthreads();
    const int lane = tid & 63, cg = tid >> 6;
    for (int c = cg; c < CCH; c += 4) {
        u32 v = hu((h2){(_Float16)tile[lane][c], (_Float16)tile[lane][66 + c]});
        xP[((size_t)c * XPW + w) * BSZ + b0 + lane] = v;
    }
}

// zero halo rows w=50,51 of every channel (8192 u32 per c, contiguous)
__global__ __launch_bounds__(256) void zero_halo_xp(u32* __restrict__ xP) {
    const int c = blockIdx.x;
    const int i = blockIdx.y * 256 + threadIdx.x;   // 2048 x u32x4 = 8192 u32
    *(u32x4*)(xP + ((size_t)c * XPW + 50) * BSZ + (size_t)i * 4) = (u32x4){0u, 0u, 0u, 0u};
}

// ---------------------------------------------------------------- packed weights
// per-c layout (u32): high @0: w1d[56] b1d[8] w2d[224] b2d[4] w3p[56] b3p[2]
//                      low @350: w1d[24] b1d[8] w2d[96]  b2d[4] w3p[24] b3p[2]
__device__ __forceinline__ u32 dupf(float v) {
    _Float16 h = (_Float16)v; return hu((h2){h, h});
}
__device__ __forceinline__ u32 pk2f(float a, float b) {
    return hu((h2){(_Float16)a, (_Float16)b});
}

__global__ __launch_bounds__(64) void prep_w(
    const float* __restrict__ hw1, const float* __restrict__ hb1,
    const float* __restrict__ hw2, const float* __restrict__ hb2,
    const float* __restrict__ hw3, const float* __restrict__ hb3,
    const float* __restrict__ lw1, const float* __restrict__ lb1,
    const float* __restrict__ lw2, const float* __restrict__ lb2,
    const float* __restrict__ lw3, const float* __restrict__ lb3,
    u32* __restrict__ wpk) {
    const int c = blockIdx.x, t = threadIdx.x;
    u32* wb = wpk + c * CWS;
    for (int i = t; i < 56; i += 64) wb[i] = dupf(hw1[c * 56 + i]);
    if (t < 8)  wb[56 + t] = dupf(hb1[c * 8 + t]);
    for (int i = t; i < 224; i += 64) wb[64 + i] = dupf(hw2[c * 224 + i]);
    if (t < 4)  wb[288 + t] = dupf(hb2[c * 4 + t]);
    for (int i = t; i < 56; i += 64) {
        int pr = i / 28, j = i - pr * 28;
        wb[292 + i] = pk2f(hw3[c * 112 + 2 * pr * 28 + j], hw3[c * 112 + (2 * pr + 1) * 28 + j]);
    }
    if (t < 2)  wb[348 + t] = pk2f(hb3[c * 4 + 2 * t], hb3[c * 4 + 2 * t + 1]);
    for (int i = t; i < 24; i += 64) wb[350 + i] = dupf(lw1[c * 24 + i]);
    if (t < 8)  wb[374 + t] = dupf(lb1[c * 8 + t]);
    for (int i = t; i < 96; i += 64) wb[382 + i] = dupf(lw2[c * 96 + i]);
    if (t < 4)  wb[478 + t] = dupf(lb2[c * 4 + t]);
    for (int i = t; i < 24; i += 64) {
        int pr = i / 12, j = i - pr * 12;
        wb[482 + i] = pk2f(lw3[c * 48 + 2 * pr * 12 + j], lw3[c * 48 + (2 * pr + 1) * 12 + j]);
    }
    if (t < 2)  wb[506 + t] = pk2f(lb3[c * 4 + 2 * t], lb3[c * 4 + 2 * t + 1]);
}

// ---------------------------------------------------------------- feature pipeline (pk-f16)
// hp1 core: PX[j] = packed x pair starting at u0+j; emits np[ic] = (colA,colB)
template<int K>
__device__ __forceinline__ void hp1_core(const u32* PX, const u32* __restrict__ w1d,
                                         const u32* __restrict__ b1d, u32 msk, u32 np[8]) {
#pragma unroll
    for (int ic = 0; ic < 8; ++ic) {
        h2 bb = uh(b1d[ic]);
        h2 AL = bb, AH = bb;
#pragma unroll
        for (int k = 0; k < K; ++k) {
            h2 w = uh(w1d[ic * K + k]);
            AL = pkfma(w, uh(PX[k]), AL);
            AH = pkfma(w, uh(PX[k + 2]), AH);
        }
        AL = pkmax0(AL); AH = pkmax0(AH);
        _Float16 cA = (_Float16)0.5f * (AL.x + AL.y);
        _Float16 cB = (_Float16)0.5f * (AH.x + AH.y);
        np[ic] = hu((h2){cA, cB}) & msk;
    }
}

// hp1 from a register window A[NA] = packed rows [w0 .. w0+NA-1], w0 = idx-(P+1)/2
template<int K, int NA>
__device__ __forceinline__ void hp1_win(const u32 A[NA], int idx,
                                        const u32* w1d, const u32* b1d, u32 np[8]) {
    u32 PX[K + 2];
#pragma unroll
    for (int j = 0; j < K + 2; ++j)
        PX[j] = (j & 1) ? A[(j + 1) / 2]
                        : __builtin_amdgcn_alignbit(A[j / 2 + 1], A[j / 2], 16);
    u32 m = ((idx < 50) ? 0xFFFFu : 0u) | ((idx + 1 < 50) ? 0xFFFF0000u : 0u);
    hp1_core<K>(PX, w1d, b1d, m, np);
}

// compile-time-idx hp1 for the prologue (handles u<0 as zeros; all folds)
template<int K, int IDX>
__device__ __forceinline__ void hp1_edge(const u32* __restrict__ xg,
                                         const u32* w1d, const u32* b1d, u32 np[8]) {
    constexpr int P = K / 2;
    u32 PX[K + 2];
#pragma unroll
    for (int j = 0; j < K + 2; ++j) {
        int u = 2 * IDX - P + j;
        u32 v;
        if (u < -1)      v = 0u;
        else if (u == -1) v = xg[0] << 16;   // (x[-1]=0, x[0])
        else if (u & 1)  v = __builtin_amdgcn_alignbit(xg[(size_t)((u + 1) / 2) * BSZ],
                                                       xg[(size_t)((u - 1) / 2) * BSZ], 16);
        else             v = xg[(size_t)(u / 2) * BSZ];
        PX[j] = v;
    }
    hp1_core<K>(PX, w1d, b1d, 0xFFFFFFFFu, np);
}

// Full branch, packed-f16, global x reads via sliding register window.
// Rolled s-loop (R4/R5: do NOT unroll).
template<int K>
__device__ __forceinline__ void run_branch_pk(const u32* __restrict__ xg,
                                              const u32* __restrict__ wb,
                                              u32* __restrict__ orow) {
    constexpr int P = K / 2;
    constexpr int NW1 = (K + 1) / 2;
    constexpr int NA = (K == 7) ? 6 : 4;       // packed-row window size
    constexpr int WB = (K == 7) ? 3 : 2;       // first window row (= idx0-(P+1)/2)
    const u32* w1d = wb;
    const u32* b1d = wb + 8 * K;
    const u32* w2d = b1d + 8;
    const u32* b2d = w2d + 32 * K;
    const u32* w3p = b2d + 4;
    const u32* b3p = w3p + 8 * K;

    u32 W1p[8][NW1];
    u32 W2d[4][K];
#pragma unroll
    for (int ic = 0; ic < 8; ++ic)
#pragma unroll
        for (int j = 0; j < NW1; ++j) W1p[ic][j] = 0u;
#pragma unroll
    for (int oc = 0; oc < 4; ++oc)
#pragma unroll
        for (int k = 0; k < K; ++k) W2d[oc][k] = 0u;

    // prologue: fill W1p so cols j hold hp1[-P+j] (zeros for negative)
    {
        u32 np[8];
        if (K == 7) {
            hp1_edge<K, 0>(xg, w1d, b1d, np);
#pragma unroll
            for (int ic = 0; ic < 8; ++ic) W1p[ic][1] = np[ic] << 16;  // (0, c0)
            hp1_edge<K, 1>(xg, w1d, b1d, np);
#pragma unroll
            for (int ic = 0; ic < 8; ++ic) W1p[ic][2] = np[ic];        // (c1, c2)
            hp1_edge<K, 3>(xg, w1d, b1d, np);
#pragma unroll
            for (int ic = 0; ic < 8; ++ic) W1p[ic][3] = np[ic];        // (c3, c4)
        } else {
            hp1_edge<K, 0>(xg, w1d, b1d, np);
#pragma unroll
            for (int ic = 0; ic < 8; ++ic) W1p[ic][0] = np[ic] << 16;  // (0, c0)
            hp1_edge<K, 1>(xg, w1d, b1d, np);
#pragma unroll
            for (int ic = 0; ic < 8; ++ic) W1p[ic][1] = np[ic];        // (c1, c2)
        }
    }

    // init sliding window: rows WB .. WB+NA-1
    u32 XA[NA];
#pragma unroll
    for (int j = 0; j < NA; ++j) XA[j] = xg[(size_t)(WB + j) * BSZ];

    h2 Pp01 = (h2)(_Float16)0.f, Pp23 = Pp01, Q01 = Pp01, Q23 = Pp01;
    const int SMAX = 23 + P;
    for (int s = 0; s <= SMAX; ++s) {
        // conv2: Y[oc] = (y2[2s], y2[2s+1])
        h2 Y[4];
#pragma unroll
        for (int oc = 0; oc < 4; ++oc) Y[oc] = uh(b2d[oc]);
#pragma unroll
        for (int ic = 0; ic < 8; ++ic) {
            u32 PW[K];
#pragma unroll
            for (int k = 0; k < K; ++k)
                PW[k] = (k & 1) ? __builtin_amdgcn_alignbit(W1p[ic][k / 2 + 1], W1p[ic][k / 2], 16)
                                : W1p[ic][k / 2];
#pragma unroll
            for (int oc = 0; oc < 4; ++oc)
#pragma unroll
                for (int k = 0; k < K; ++k)
                    Y[oc] = pkfma(uh(w2d[(oc * 8 + ic) * K + k]), uh(PW[k]), Y[oc]);
        }
        // hp2 (pool+relu, duplicated) -> shift W2d, append
#pragma unroll
        for (int oc = 0; oc < 4; ++oc) {
            h2 Yr = pkmax0(Y[oc]);
            _Float16 hv = (_Float16)0.5f * (Yr.x + Yr.y);
            u32 d = hu((h2){hv, hv});
            d = (s <= 24) ? d : 0u;
#pragma unroll
            for (int k = 0; k < K - 1; ++k) W2d[oc][k] = W2d[oc][k + 1];
            W2d[oc][K - 1] = d;
        }
        // conv3 at p = s-P, packed over oc pairs
        int p = s - P;
        if (p >= 0) {
            h2 Y01 = uh(b3p[0]), Y23 = uh(b3p[1]);
#pragma unroll
            for (int ic = 0; ic < 4; ++ic)
#pragma unroll
                for (int k = 0; k < K; ++k) {
                    h2 wv = uh(W2d[ic][k]);
                    Y01 = pkfma(uh(w3p[ic * K + k]), wv, Y01);
                    Y23 = pkfma(uh(w3p[4 * K + ic * K + k]), wv, Y23);
                }
            Y01 = pkmax0(Y01); Y23 = pkmax0(Y23);
            if ((p & 1) == 0) { Pp01 = Y01; Pp23 = Y23; }
            else {
                h2 hf = (h2)(_Float16)0.5f;
                h2 O01 = (Pp01 + Y01) * hf;
                h2 O23 = (Pp23 + Y23) * hf;
                int t = p >> 1;
                if ((t & 1) == 0) { Q01 = O01; Q23 = O23; }
                else {
                    int w = t >> 1;
                    orow[0 * 6 + w] = hu((h2){Q01.x, O01.x});
                    orow[1 * 6 + w] = hu((h2){Q01.y, O01.y});
                    orow[2 * 6 + w] = hu((h2){Q23.x, O23.x});
                    orow[3 * 6 + w] = hu((h2){Q23.y, O23.y});
                }
            }
        }
        // advance W1p by one pair (= 2 cols) using the register window
        if (s < SMAX) {
            u32 np[8];
            hp1_win<K, NA>(XA, 2 * s + P + 2, w1d, b1d, np);
#pragma unroll
            for (int ic = 0; ic < 8; ++ic) {
#pragma unroll
                for (int j = 0; j < NW1 - 1; ++j) W1p[ic][j] = W1p[ic][j + 1];
                W1p[ic][NW1 - 1] = np[ic];
            }
            // slide window by 2 rows, load 2 new rows (coalesced dword)
#pragma unroll
            for (int j = 0; j < NA - 2; ++j) XA[j] = XA[j + 2];
            XA[NA - 2] = xg[(size_t)(WB + 2 * s + NA) * BSZ];
            XA[NA - 1] = xg[(size_t)(WB + 2 * s + NA + 1) * BSZ];
        }
    }
}

// feats2 blocked layout: element (b, k = c*112 + f) at
//   feats2[(c*14 + (f>>3)) * ROWE + b*8 + (f&7)]
// blockIdx.z: 0 = high branch (K=7, chunks 0..5), 1 = low branch + residual (6..13)
__global__ __launch_bounds__(256, 2) void feats_kernel(
    const u32* __restrict__ xP, const u32* __restrict__ wpk,
    f16* __restrict__ feats2) {
    __shared__ u32 obufw[256 * OSTR];   // 25,600 B
    const int c = blockIdx.x;
    const int tid = threadIdx.x;
    const int b = blockIdx.y * 256 + tid;

    const u32* xg = xP + (size_t)c * XPW * BSZ + b;   // packed row w at xg[w*BSZ]
    const u32* wb = wpk + c * CWS;
    u32* orow = obufw + tid * OSTR;
    u32* dst = (u32*)feats2 + (size_t)c * 14 * (ROWE / 2) + (size_t)b * 4;

    if (blockIdx.z == 0) {
        // high branch (K=7) -> chunks 0..5
        run_branch_pk<7>(xg, wb, orow);
        u32 v[24];
#pragma unroll
        for (int j = 0; j < 24; ++j) v[j] = orow[j];   // same-thread RAW, no barrier
#pragma unroll
        for (int ch = 0; ch < 6; ++ch)
            *(u32x4*)(dst + (size_t)ch * (ROWE / 2)) =
                (u32x4){v[ch * 4], v[ch * 4 + 1], v[ch * 4 + 2], v[ch * 4 + 3]};
    } else {
        // low branch (K=3) -> chunks 6..11
        run_branch_pk<3>(xg, wb + 350, orow);
        u32 v[24];
#pragma unroll
        for (int j = 0; j < 24; ++j) v[j] = orow[j];
#pragma unroll
        for (int ch = 0; ch < 6; ++ch)
            *(u32x4*)(dst + (size_t)(6 + ch) * (ROWE / 2)) =
                (u32x4){v[ch * 4], v[ch * 4 + 1], v[ch * 4 + 2], v[ch * 4 + 3]};
        // residual pooling -> chunks 12..13
        u32 orr[6];
#pragma unroll
        for (int t2 = 0; t2 < 6; ++t2) {
            h2 S0 = uh(xg[(size_t)(8 * t2 + 0) * BSZ]) + uh(xg[(size_t)(8 * t2 + 1) * BSZ]) +
                    uh(xg[(size_t)(8 * t2 + 2) * BSZ]) + uh(xg[(size_t)(8 * t2 + 3) * BSZ]);
            h2 S1 = uh(xg[(size_t)(8 * t2 + 4) * BSZ]) + uh(xg[(size_t)(8 * t2 + 5) * BSZ]) +
                    uh(xg[(size_t)(8 * t2 + 6) * BSZ]) + uh(xg[(size_t)(8 * t2 + 7) * BSZ]);
            _Float16 o0 = (_Float16)0.125f * (S0.x + S0.y);
            _Float16 o1 = (_Float16)0.125f * (S1.x + S1.y);
            orr[t2] = hu((h2){o0, o1});
        }
        *(u32x4*)(dst + (size_t)12 * (ROWE / 2)) = (u32x4){orr[0], orr[1], orr[2], orr[3]};
        *(u32x4*)(dst + (size_t)13 * (ROWE / 2)) = (u32x4){orr[4], orr[5], 0u, 0u};
    }
}

// zero the pad chunk-rows (k = 7392..7423 -> rows 924..927)
__global__ void zero_pad2(f16* __restrict__ feats2) {
    int idx = blockIdx.x * 256 + threadIdx.x;
    u32* dst = (u32*)(feats2 + (size_t)(CCH * 14) * ROWE);
    if (idx < (4 * ROWE * 2) / 16)
        *(u32x4*)(dst + idx * 4) = (u32x4){0u, 0u, 0u, 0u};
}

// convert fw1 (1936 x 7128 f32) -> padded f16 (2048 x 7424) with per-c pad
__global__ void cvt_fw1(const float* __restrict__ fw1, f16* __restrict__ dst) {
    int n = blockIdx.y;
    int kp = blockIdx.x * 256 + threadIdx.x;
    if (kp >= KP2) return;
    int c2 = kp / FPC, f = kp - c2 * FPC;
    float v = 0.f;
    if (n < NOUT && kp < KF2 && f < 108)
        v = fw1[(size_t)n * KFEAT + c2 * 108 + f];
    dst[(size_t)n * KP2 + kp] = (f16)v;
}

// ---------------------------------------------------------------- FC1 GEMM
// BM=64, BN=128 -> grid (64,16) = 1024 blocks = 4 blocks/CU (R9: 512 blocks =
// 2/CU was the bottleneck; m102 shape curve says blocks/CU dominates).
// 4 waves, each 32M x 64N: 2 m-frags x 4 n-frags, acc = 8 f32x4 = 32 VGPR.
__global__ __launch_bounds__(256, 4) void fc1_gemm(
    const f16* __restrict__ A, const f16* __restrict__ Bw,
    const float* __restrict__ fb1, f16* __restrict__ H) {
    __shared__ f16 lds_a[64 * 32];      // 4 KB
    __shared__ f16 lds_b[128 * 32];     // 8 KB
    const int tid = threadIdx.x;
    const int bm = blockIdx.x;  // 64 tiles of M (64 rows each)
    const int bn = blockIdx.y;  // 16 tiles of N (128 cols each)
    const int wid = tid >> 6, lane = tid & 63;
    const int wm = wid >> 1, wn = wid & 1;

    f32x4 acc[2][4];
#pragma unroll
    for (int i = 0; i < 2; ++i)
#pragma unroll
        for (int j = 0; j < 4; ++j) acc[i][j] = (f32x4){0.f, 0.f, 0.f, 0.f};

    const f16* Bbase = Bw + (size_t)bn * 128 * KP2;
    const int l15 = lane & 15, lhi = lane >> 4;

    // A staging: 64 rows x 32 k = 4 KB = 256 x 16B chunks (1 per thread)
    const int arow = tid >> 2, akc = tid & 3;
    // B staging: 128 rows x 32 k = 8 KB = 512 chunks (2 per thread)
    const int brow0 = tid >> 2, bkc0 = tid & 3;
    const int brow1 = (256 + tid) >> 2, bkc1 = tid & 3;

    for (int k0 = 0; k0 < KP2; k0 += 32) {
        __syncthreads();
        gload_lds16(A + (size_t)((k0 >> 3) + akc) * ROWE + (size_t)(bm * 64 + arow) * 8,
                    (char*)lds_a + tid * 16);
        gload_lds16(Bbase + (size_t)brow0 * KP2 + k0 + bkc0 * 8, (char*)lds_b + tid * 16);
        gload_lds16(Bbase + (size_t)brow1 * KP2 + k0 + bkc1 * 8, (char*)lds_b + (256 + tid) * 16);
        __syncthreads();

        f16x8 af[2], bf[4];
#pragma unroll
        for (int i = 0; i < 2; ++i) {
            int m = wm * 32 + i * 16 + l15;
            af[i] = *(const f16x8*)(lds_a + m * 32 + lhi * 8);
        }
#pragma unroll
        for (int j = 0; j < 4; ++j) {
            int n = wn * 64 + j * 16 + l15;
            bf[j] = *(const f16x8*)(lds_b + n * 32 + lhi * 8);
        }
#pragma unroll
        for (int i = 0; i < 2; ++i)
#pragma unroll
            for (int j = 0; j < 4; ++j)
                acc[i][j] = __builtin_amdgcn_mfma_f32_16x16x32_f16(af[i], bf[j], acc[i][j], 0, 0, 0);
    }

    // epilogue: C/D layout col = lane&15, row = (lane>>4)*4 + r
#pragma unroll
    for (int i = 0; i < 2; ++i) {
#pragma unroll
        for (int j = 0; j < 4; ++j) {
            int n = bn * 128 + wn * 64 + j * 16 + l15;
            float bias = (n < NOUT) ? fb1[n] : 0.f;
#pragma unroll
            for (int r = 0; r < 4; ++r) {
                int m = bm * 64 + wm * 32 + i * 16 + lhi * 4 + r;
                float v = acc[i][j][r] + bias;
                H[(size_t)m * NPAD + n] = (f16)fmaxf(v, 0.f);
            }
        }
    }
}

// ---------------------------------------------------------------- FC2
__global__ __launch_bounds__(64) void fc2_kernel(const f16* __restrict__ H,
                                                 const float* __restrict__ fw2,
                                                 const float* __restrict__ fb2,
                                                 float* __restrict__ out) {
    const int b = blockIdx.x;
    const int t = threadIdx.x;
    const f16* hb = H + (size_t)b * NPAD;
    float acc[14];
#pragma unroll
    for (int o = 0; o < 14; ++o) acc[o] = 0.f;
    for (int k = t; k < NOUT; k += 64) {
        float hv = (float)hb[k];
#pragma unroll
        for (int o = 0; o < 14; ++o) acc[o] += hv * fw2[o * NOUT + k];
    }
#pragma unroll
    for (int o = 0; o < 14; ++o) {
        float v = acc[o];
#pragma unroll
        for (int off = 32; off > 0; off >>= 1) v += __shfl_down(v, off, 64);
        if (t == 0) out[b * 14 + o] = v + fb2[o];
    }
}

// ---------------------------------------------------------------- launcher
extern "C" void kernel_launch(void* const* d_in, const int* in_sizes, int n_in,
                              void* d_out, int out_size, void* d_ws, size_t ws_size,
                              hipStream_t stream) {
    const float* x   = (const float*)d_in[0];
    const float* hw1 = (const float*)d_in[1];
    const float* hb1 = (const float*)d_in[2];
    const float* hw2 = (const float*)d_in[3];
    const float* hb2 = (const float*)d_in[4];
    const float* hw3 = (const float*)d_in[5];
    const float* hb3 = (const float*)d_in[6];
    const float* lw1 = (const float*)d_in[7];
    const float* lb1 = (const float*)d_in[8];
    const float* lw2 = (const float*)d_in[9];
    const float* lb2 = (const float*)d_in[10];
    const float* lw3 = (const float*)d_in[11];
    const float* lb3 = (const float*)d_in[12];
    const float* fw1 = (const float*)d_in[13];
    const float* fb1 = (const float*)d_in[14];
    const float* fw2 = (const float*)d_in[15];
    const float* fb2 = (const float*)d_in[16];

    // workspace (byte offsets; aliases exploit disjoint lifetimes):
    // [0, 60.8M)          feats2
    // [60.8M, 77.6M)      h f16 (16.8M)
    // [114.9M, ...)       xP (56.23M) -> later fw1H (30.4M); wpk directly after xP
    //                     (hp1 masked overreads past xP land inside wpk region)
    char* wsb = (char*)d_ws;
    f16*  feats2 = (f16*)wsb;
    char* reg2   = wsb + (size_t)NCH2 * ROWE * 2;           // 60,817,408
    f16*  h      = (f16*)reg2;
    char* reg3   = reg2 + 54067200;
    u32*  xP     = (u32*)reg3;
    f16*  fw1H   = (f16*)reg3;                               // aliases xP (after feats)
    u32*  wpk    = (u32*)(reg3 + (size_t)CCH * XPW * BSZ * 4);

    xpose_pack<<<dim3(50, BSZ / 64), 256, 0, stream>>>(x, xP);
    zero_halo_xp<<<dim3(CCH, 8), 256, 0, stream>>>(xP);
    prep_w<<<dim3(CCH), 64, 0, stream>>>(hw1, hb1, hw2, hb2, hw3, hb3,
                                         lw1, lb1, lw2, lb2, lw3, lb3, wpk);
    feats_kernel<<<dim3(CCH, BSZ / 256, 2), 256, 0, stream>>>(xP, wpk, feats2);
    zero_pad2<<<dim3(64), 256, 0, stream>>>(feats2);
    cvt_fw1<<<dim3((KP2 + 255) / 256, NPAD), 256, 0, stream>>>(fw1, fw1H);  // xP dead now
    fc1_gemm<<<dim3(BSZ / 64, NPAD / 128), 256, 0, stream>>>(feats2, fw1H, fb1, h);
    fc2_kernel<<<dim3(BSZ), 64, 0, stream>>>(h, fw2, fb2, (float*)d_out);
}